// Round 11
// baseline (95.001 us; speedup 1.0000x reference)
//
#include <hip/hip_runtime.h>
#include <hip/hip_bf16.h>

#define S_LEN 512
#define EMB   512
#define NHEAD 8
#define DPH   64
#define NREL  3
#define BATCH 8

typedef __attribute__((ext_vector_type(8))) short bf16x8;
typedef __attribute__((ext_vector_type(4))) float f32x4;

__device__ __forceinline__ float bf2f(unsigned short u) {
    union { unsigned int i; float f; } cv;
    cv.i = ((unsigned int)u) << 16;
    return cv.f;
}
__device__ __forceinline__ unsigned short f2bf(float f) {
    __hip_bfloat16 h = __float2bfloat16(f);
    return *reinterpret_cast<unsigned short*>(&h);
}

// ---------------------------------------------------------------------------
// Weight transpose: Wt[z][n][k] (bf16) = W[z][k][n] (f32), z in {q,k,v,o}.
// ---------------------------------------------------------------------------
__global__ __launch_bounds__(256) void transpose_w(
    const float* __restrict__ Wq, const float* __restrict__ Wk,
    const float* __restrict__ Wv, const float* __restrict__ Wo,
    unsigned short* __restrict__ Wt)
{
    const int z = blockIdx.z;
    const float* W = (z == 0) ? Wq : (z == 1) ? Wk : (z == 2) ? Wv : Wo;
    unsigned short* dst = Wt + (size_t)z * EMB * EMB;

    __shared__ float tile[64][65];
    const int n0 = blockIdx.x * 64, k0 = blockIdx.y * 64;
    const int t = threadIdx.x;
    const int cr = t >> 4, cc = (t & 15) * 4;

    #pragma unroll
    for (int it = 0; it < 4; ++it) {
        int r = cr + it * 16;
        float4 v = *reinterpret_cast<const float4*>(W + (size_t)(k0 + r) * EMB + n0 + cc);
        tile[r][cc + 0] = v.x; tile[r][cc + 1] = v.y;
        tile[r][cc + 2] = v.z; tile[r][cc + 3] = v.w;
    }
    __syncthreads();
    #pragma unroll
    for (int it = 0; it < 4; ++it) {
        int n = cr + it * 16;
        ushort4 o;
        o.x = f2bf(tile[cc + 0][n]); o.y = f2bf(tile[cc + 1][n]);
        o.z = f2bf(tile[cc + 2][n]); o.w = f2bf(tile[cc + 3][n]);
        *reinterpret_cast<ushort4*>(dst + (size_t)(n0 + n) * EMB + k0 + cc) = o;
    }
}

// ---------------------------------------------------------------------------
// MFMA projection GEMM. 128x64 tile, 4 waves 2x2.
// z==2 (V) writes TRANSPOSED per-head: vbT[(b*NHEAD+h)*DPH + d][s] (bf16).
// ---------------------------------------------------------------------------
__global__ __launch_bounds__(256) void gemm_proj_mfma(
    const float* __restrict__ Aq, const float* __restrict__ Ak, const float* __restrict__ Av,
    const unsigned short* __restrict__ Wt,
    const float* __restrict__ bqp, const float* __restrict__ bkp, const float* __restrict__ bvp,
    unsigned short* __restrict__ oq, unsigned short* __restrict__ okp, unsigned short* __restrict__ ov)
{
    const int z = blockIdx.z;
    const float* A = (z == 0) ? Aq : (z == 1) ? Ak : Av;
    const unsigned short* W = Wt + (size_t)z * EMB * EMB;
    const float* bias = (z == 0) ? bqp : (z == 1) ? bkp : bvp;
    unsigned short* out = (z == 0) ? oq : (z == 1) ? okp : ov;

    const int n0 = blockIdx.x * 64;
    const int m0 = blockIdx.y * 128;
    const int tid = threadIdx.x;
    const int lane = tid & 63;
    const int wid = tid >> 6;
    const int wr = wid >> 1, wc = wid & 1;

    __shared__ __align__(16) unsigned char smA[128 * 64 * 2];
    __shared__ __align__(16) unsigned char smB[64 * 64 * 2];

    f32x4 acc[4][2] = {};

    for (int k0 = 0; k0 < EMB; k0 += 64) {
        __syncthreads();
        #pragma unroll
        for (int it = 0; it < 4; ++it) {
            int w = it * 256 + tid;
            int row = w >> 3, kc = w & 7;
            const float* src = A + (size_t)(m0 + row) * EMB + k0 + kc * 8;
            float4 v0 = *reinterpret_cast<const float4*>(src);
            float4 v1 = *reinterpret_cast<const float4*>(src + 4);
            union { unsigned short s[8]; uint4 u; } p;
            p.s[0] = f2bf(v0.x); p.s[1] = f2bf(v0.y); p.s[2] = f2bf(v0.z); p.s[3] = f2bf(v0.w);
            p.s[4] = f2bf(v1.x); p.s[5] = f2bf(v1.y); p.s[6] = f2bf(v1.z); p.s[7] = f2bf(v1.w);
            unsigned byte = ((unsigned)row << 7) + ((unsigned)kc << 4);
            byte ^= (unsigned)((row & 7) << 4);
            *reinterpret_cast<uint4*>(smA + byte) = p.u;
        }
        #pragma unroll
        for (int it = 0; it < 2; ++it) {
            int w = it * 256 + tid;
            int row = w >> 3, kc = w & 7;
            uint4 raw = *reinterpret_cast<const uint4*>(W + (size_t)(n0 + row) * EMB + k0 + kc * 8);
            unsigned byte = ((unsigned)row << 7) + ((unsigned)kc << 4);
            byte ^= (unsigned)((row & 7) << 4);
            *reinterpret_cast<uint4*>(smB + byte) = raw;
        }
        __syncthreads();

        #pragma unroll
        for (int ks = 0; ks < 2; ++ks) {
            bf16x8 bfrag[2];
            #pragma unroll
            for (int ni = 0; ni < 2; ++ni) {
                int col = wc * 32 + ni * 16 + (lane & 15);
                unsigned byte = ((unsigned)col << 7) + (unsigned)(ks << 6) + (unsigned)((lane >> 4) << 4);
                byte ^= (unsigned)((col & 7) << 4);
                bfrag[ni] = *reinterpret_cast<const bf16x8*>(smB + byte);
            }
            #pragma unroll
            for (int mi = 0; mi < 4; ++mi) {
                int row = wr * 64 + mi * 16 + (lane & 15);
                unsigned byte = ((unsigned)row << 7) + (unsigned)(ks << 6) + (unsigned)((lane >> 4) << 4);
                byte ^= (unsigned)((row & 7) << 4);
                bf16x8 afrag = *reinterpret_cast<const bf16x8*>(smA + byte);
                #pragma unroll
                for (int ni = 0; ni < 2; ++ni)
                    acc[mi][ni] = __builtin_amdgcn_mfma_f32_16x16x32_bf16(afrag, bfrag[ni], acc[mi][ni], 0, 0, 0);
            }
        }
    }

    if (z == 2) {
        #pragma unroll
        for (int ni = 0; ni < 2; ++ni) {
            int colg = n0 + wc * 32 + ni * 16 + (lane & 15);
            float bj = bias[colg];
            int hh = colg >> 6, dd = colg & 63;
            #pragma unroll
            for (int mi = 0; mi < 4; ++mi) {
                int rbase = m0 + wr * 64 + mi * 16 + ((lane >> 4) << 2);
                int bb = rbase >> 9, ss = rbase & 511;
                ushort4 o;
                o.x = f2bf(acc[mi][ni][0] + bj);
                o.y = f2bf(acc[mi][ni][1] + bj);
                o.z = f2bf(acc[mi][ni][2] + bj);
                o.w = f2bf(acc[mi][ni][3] + bj);
                *reinterpret_cast<ushort4*>(out + ((size_t)(bb * NHEAD + hh) * DPH + dd) * S_LEN + ss) = o;
            }
        }
    } else {
        #pragma unroll
        for (int ni = 0; ni < 2; ++ni) {
            int colg = n0 + wc * 32 + ni * 16 + (lane & 15);
            float bj = bias[colg];
            #pragma unroll
            for (int mi = 0; mi < 4; ++mi) {
                int rbase = m0 + wr * 64 + mi * 16 + ((lane >> 4) << 2);
                #pragma unroll
                for (int q = 0; q < 4; ++q)
                    out[(size_t)(rbase + q) * EMB + colg] = f2bf(acc[mi][ni][q] + bj);
            }
        }
    }
}

// ---------------------------------------------------------------------------
// MFMA output GEMM (validated round 5).
// ---------------------------------------------------------------------------
__global__ __launch_bounds__(256) void gemm_out_mfma(
    const unsigned short* __restrict__ A,
    const unsigned short* __restrict__ W,
    const float* __restrict__ bias,
    float* __restrict__ out)
{
    const int n0 = blockIdx.x * 64;
    const int m0 = blockIdx.y * 128;
    const int tid = threadIdx.x;
    const int lane = tid & 63;
    const int wid = tid >> 6;
    const int wr = wid >> 1, wc = wid & 1;

    __shared__ __align__(16) unsigned char smA[128 * 64 * 2];
    __shared__ __align__(16) unsigned char smB[64 * 64 * 2];

    f32x4 acc[4][2] = {};

    for (int k0 = 0; k0 < EMB; k0 += 64) {
        __syncthreads();
        #pragma unroll
        for (int it = 0; it < 4; ++it) {
            int w = it * 256 + tid;
            int row = w >> 3, kc = w & 7;
            uint4 raw = *reinterpret_cast<const uint4*>(A + (size_t)(m0 + row) * EMB + k0 + kc * 8);
            unsigned byte = ((unsigned)row << 7) + ((unsigned)kc << 4);
            byte ^= (unsigned)((row & 7) << 4);
            *reinterpret_cast<uint4*>(smA + byte) = raw;
        }
        #pragma unroll
        for (int it = 0; it < 2; ++it) {
            int w = it * 256 + tid;
            int row = w >> 3, kc = w & 7;
            uint4 raw = *reinterpret_cast<const uint4*>(W + (size_t)(n0 + row) * EMB + k0 + kc * 8);
            unsigned byte = ((unsigned)row << 7) + ((unsigned)kc << 4);
            byte ^= (unsigned)((row & 7) << 4);
            *reinterpret_cast<uint4*>(smB + byte) = raw;
        }
        __syncthreads();

        #pragma unroll
        for (int ks = 0; ks < 2; ++ks) {
            bf16x8 bfrag[2];
            #pragma unroll
            for (int ni = 0; ni < 2; ++ni) {
                int col = wc * 32 + ni * 16 + (lane & 15);
                unsigned byte = ((unsigned)col << 7) + (unsigned)(ks << 6) + (unsigned)((lane >> 4) << 4);
                byte ^= (unsigned)((col & 7) << 4);
                bfrag[ni] = *reinterpret_cast<const bf16x8*>(smB + byte);
            }
            #pragma unroll
            for (int mi = 0; mi < 4; ++mi) {
                int row = wr * 64 + mi * 16 + (lane & 15);
                unsigned byte = ((unsigned)row << 7) + (unsigned)(ks << 6) + (unsigned)((lane >> 4) << 4);
                byte ^= (unsigned)((row & 7) << 4);
                bf16x8 afrag = *reinterpret_cast<const bf16x8*>(smA + byte);
                #pragma unroll
                for (int ni = 0; ni < 2; ++ni)
                    acc[mi][ni] = __builtin_amdgcn_mfma_f32_16x16x32_bf16(afrag, bfrag[ni], acc[mi][ni], 0, 0, 0);
            }
        }
    }

    #pragma unroll
    for (int ni = 0; ni < 2; ++ni) {
        int colg = n0 + wc * 32 + ni * 16 + (lane & 15);
        float bj = bias[colg];
        #pragma unroll
        for (int mi = 0; mi < 4; ++mi) {
            int rbase = m0 + wr * 64 + mi * 16 + ((lane >> 4) << 2);
            #pragma unroll
            for (int q = 0; q < 4; ++q)
                out[(size_t)(rbase + q) * EMB + colg] = acc[mi][ni][q] + bj;
        }
    }
}

// ---------------------------------------------------------------------------
// MFMA relation-aware flash attention, v5: barrier-free main loop.
// Block = 256 thr = 4 waves, 16 q-rows, 4-way t-split (wave = 2 tiles).
// K/V fragments loaded DIRECTLY from global (L2/L3-resident; no LDS staging,
// no loop barriers). vf loads issued after QK so latency hides under softmax.
// Epilogue: 4-way flash merge through LDS (one barrier pair).
// grid (32, 8, 8) = 2048 blocks -> no grid-size occupancy cap.
// ---------------------------------------------------------------------------
__global__ __launch_bounds__(256) void attn_mfma(
    const unsigned short* __restrict__ qb,
    const unsigned short* __restrict__ kb,
    const unsigned short* __restrict__ vbT,
    const int* __restrict__ rel,
    const float* __restrict__ rel_k, const float* __restrict__ rel_v,
    unsigned short* __restrict__ ob)
{
    const int s0 = blockIdx.x * 16;
    const int h  = blockIdx.y;
    const int b  = blockIdx.z;
    const int tid = threadIdx.x;
    const int lane = tid & 63;
    const int wid = tid >> 6;          // t-group 0..3 (2 tiles each)
    const int sl = lane & 15;
    const int tg = lane >> 4;

    __shared__ __align__(16) unsigned char smQ[16 * 128];      // 2 KB swizzled
    __shared__ __align__(16) unsigned char smP[4 * 16 * 128];  // per-wave P
    __shared__ float accPart[3][16][64];                       // groups 1..3
    __shared__ float stats[4][5][16];                          // m,l,es0..2
    __shared__ float qrel_s[16][4];
    __shared__ float relv_s[NREL][64];

    const unsigned short* qsrc  = qb + ((size_t)(b * S_LEN + s0)) * EMB + h * DPH;
    const unsigned short* ksrc  = kb + ((size_t)b * S_LEN) * EMB + h * DPH;
    const unsigned short* vsrcT = vbT + (size_t)(b * NHEAD + h) * DPH * S_LEN;

    // --- stage Q (16x64 bf16, swizzled): 128 uint4 ---
    if (tid < 128) {
        int row = tid >> 3, kc = tid & 7;
        uint4 raw = *reinterpret_cast<const uint4*>(qsrc + (size_t)row * EMB + kc * 8);
        unsigned byte = ((unsigned)row << 7) + ((unsigned)kc << 4);
        byte ^= (unsigned)((row & 7) << 4);
        *reinterpret_cast<uint4*>(smQ + byte) = raw;
    }
    if (tid < NREL * 64) {
        int rr = tid >> 6, d = tid & 63;
        relv_s[rr][d] = rel_v[rr * DPH + d];
    }
    __syncthreads();
    if (tid < 48) {
        int r = tid / 3, rr = tid - 3 * (tid / 3);
        float s = 0.f;
        #pragma unroll
        for (int dc = 0; dc < 32; ++dc) {
            unsigned byte = ((unsigned)r << 7) + (unsigned)(dc << 2);
            byte ^= (unsigned)((r & 7) << 4);
            unsigned u = *reinterpret_cast<const unsigned*>(smQ + byte);
            s += bf2f((unsigned short)(u & 0xffff)) * rel_k[rr * DPH + dc * 2]
               + bf2f((unsigned short)(u >> 16))   * rel_k[rr * DPH + dc * 2 + 1];
        }
        qrel_s[r][rr] = s;
    }
    __syncthreads();

    const float qr0 = qrel_s[sl][0], qr1 = qrel_s[sl][1], qr2 = qrel_s[sl][2];

    bf16x8 qfrag[2];
    #pragma unroll
    for (int ks = 0; ks < 2; ++ks) {
        unsigned byte = ((unsigned)sl << 7) + (unsigned)(ks << 6) + (unsigned)(tg << 4);
        byte ^= (unsigned)((sl & 7) << 4);
        qfrag[ks] = *reinterpret_cast<const bf16x8*>(smQ + byte);
    }

    const int* rrow_s = rel + ((size_t)(b * S_LEN + s0 + sl)) * S_LEN;
    const unsigned pbase = (unsigned)(wid * 2048);
    const float scale = 0.125f;

    float m_run = -1e30f, l_run = 0.f;
    float es[NREL] = {};
    f32x4 acc_pv[4] = {};

    #pragma unroll
    for (int i = 0; i < 2; ++i) {
        const int t0 = (wid * 2 + i) * 64;

        // K fragments + rel, straight from global (L2-resident)
        bf16x8 kf[2][4];
        #pragma unroll
        for (int ks = 0; ks < 2; ++ks)
            #pragma unroll
            for (int t4 = 0; t4 < 4; ++t4)
                kf[ks][t4] = *reinterpret_cast<const bf16x8*>(
                    ksrc + (size_t)(t0 + t4 * 16 + sl) * EMB + ks * 32 + tg * 8);
        int4 rr[4];
        #pragma unroll
        for (int t4 = 0; t4 < 4; ++t4)
            rr[t4] = *reinterpret_cast<const int4*>(rrow_s + t0 + t4 * 16 + tg * 4);

        // QK^T: C[t][s]
        f32x4 sacc[4] = {};
        #pragma unroll
        for (int ks = 0; ks < 2; ++ks)
            #pragma unroll
            for (int t4 = 0; t4 < 4; ++t4)
                sacc[t4] = __builtin_amdgcn_mfma_f32_16x16x32_bf16(kf[ks][t4], qfrag[ks], sacc[t4], 0, 0, 0);

        // V fragments issue now -> latency hides under softmax (kf regs reused)
        bf16x8 vf[2][4];
        #pragma unroll
        for (int ks = 0; ks < 2; ++ks)
            #pragma unroll
            for (int dt = 0; dt < 4; ++dt)
                vf[ks][dt] = *reinterpret_cast<const bf16x8*>(
                    vsrcT + (size_t)(dt * 16 + sl) * S_LEN + t0 + ks * 32 + tg * 8);

        int rvv[4][4];
        float mt = -1e30f;
        #pragma unroll
        for (int t4 = 0; t4 < 4; ++t4) {
            int rv[4] = {rr[t4].x, rr[t4].y, rr[t4].z, rr[t4].w};
            #pragma unroll
            for (int j = 0; j < 4; ++j) {
                int r = rv[j]; r = r < 0 ? 0 : (r > 2 ? 2 : r);
                rvv[t4][j] = r;
                float qa = (r == 0) ? qr0 : ((r == 1) ? qr1 : qr2);
                float v = (sacc[t4][j] + qa) * scale;
                sacc[t4][j] = v;
                mt = fmaxf(mt, v);
            }
        }
        mt = fmaxf(mt, __shfl_xor(mt, 16));
        mt = fmaxf(mt, __shfl_xor(mt, 32));

        float mn = fmaxf(m_run, mt);
        float al = __expf(m_run - mn);
        m_run = mn;

        float ps = 0.f;
        #pragma unroll
        for (int t4 = 0; t4 < 4; ++t4)
            #pragma unroll
            for (int j = 0; j < 4; ++j) {
                float p = __expf(sacc[t4][j] - mn);
                sacc[t4][j] = p;
                ps += p;
            }
        float pst = ps;
        pst += __shfl_xor(pst, 16);
        pst += __shfl_xor(pst, 32);
        l_run = l_run * al + pst;

        #pragma unroll
        for (int r2 = 0; r2 < NREL; ++r2) {
            float e2 = es[r2] * al;
            #pragma unroll
            for (int t4 = 0; t4 < 4; ++t4)
                #pragma unroll
                for (int j = 0; j < 4; ++j)
                    e2 += (rvv[t4][j] == r2) ? sacc[t4][j] : 0.f;
            es[r2] = e2;
        }

        float al_s[4];
        #pragma unroll
        for (int r = 0; r < 4; ++r) al_s[r] = __shfl(al, tg * 4 + r);
        #pragma unroll
        for (int dt = 0; dt < 4; ++dt)
            #pragma unroll
            for (int r = 0; r < 4; ++r) acc_pv[dt][r] *= al_s[r];

        // P -> LDS bf16 (per-wave region; same-wave write->read, no barrier)
        #pragma unroll
        for (int t4 = 0; t4 < 4; ++t4)
            #pragma unroll
            for (int pr = 0; pr < 2; ++pr) {
                unsigned u = (unsigned)f2bf(sacc[t4][2 * pr]) |
                             ((unsigned)f2bf(sacc[t4][2 * pr + 1]) << 16);
                unsigned byte = pbase + ((unsigned)sl << 7) + (unsigned)(t4 * 32 + tg * 8 + pr * 4);
                byte ^= (unsigned)((sl & 7) << 4);
                *reinterpret_cast<unsigned*>(smP + byte) = u;
            }

        // PV: acc[s][d] += P[s][t] V[t][d]
        #pragma unroll
        for (int ks = 0; ks < 2; ++ks) {
            unsigned pbyte = pbase + ((unsigned)sl << 7) + (unsigned)(ks << 6) + (unsigned)(tg << 4);
            pbyte ^= (unsigned)((sl & 7) << 4);
            bf16x8 pf = *reinterpret_cast<const bf16x8*>(smP + pbyte);
            #pragma unroll
            for (int dt = 0; dt < 4; ++dt)
                acc_pv[dt] = __builtin_amdgcn_mfma_f32_16x16x32_bf16(pf, vf[ks][dt], acc_pv[dt], 0, 0, 0);
        }
    }

    // es: per-lane partial over its t-quarter -> full half-row sum
    #pragma unroll
    for (int r2 = 0; r2 < NREL; ++r2) {
        es[r2] += __shfl_xor(es[r2], 16);
        es[r2] += __shfl_xor(es[r2], 32);
    }

    // ---- publish partials & 4-way merge ----
    if (wid > 0) {
        #pragma unroll
        for (int dt = 0; dt < 4; ++dt)
            #pragma unroll
            for (int r = 0; r < 4; ++r)
                accPart[wid - 1][tg * 4 + r][dt * 16 + sl] = acc_pv[dt][r];
    }
    if (tg == 0) {
        stats[wid][0][sl] = m_run;
        stats[wid][1][sl] = l_run;
        stats[wid][2][sl] = es[0];
        stats[wid][3][sl] = es[1];
        stats[wid][4][sl] = es[2];
    }
    __syncthreads();

    if (wid == 0) {
        unsigned short* dst = ob + ((size_t)(b * S_LEN + s0)) * EMB + h * DPH;
        #pragma unroll
        for (int r = 0; r < 4; ++r) {
            const int row = tg * 4 + r;
            float m0 = stats[0][0][row], m1 = stats[1][0][row];
            float m2 = stats[2][0][row], m3 = stats[3][0][row];
            float mm = fmaxf(fmaxf(m0, m1), fmaxf(m2, m3));
            float a0 = __expf(m0 - mm), a1 = __expf(m1 - mm);
            float a2 = __expf(m2 - mm), a3 = __expf(m3 - mm);
            float linv = 1.f / (a0 * stats[0][1][row] + a1 * stats[1][1][row]
                              + a2 * stats[2][1][row] + a3 * stats[3][1][row]);
            float e0 = a0 * stats[0][2][row] + a1 * stats[1][2][row] + a2 * stats[2][2][row] + a3 * stats[3][2][row];
            float e1 = a0 * stats[0][3][row] + a1 * stats[1][3][row] + a2 * stats[2][3][row] + a3 * stats[3][3][row];
            float e2 = a0 * stats[0][4][row] + a1 * stats[1][4][row] + a2 * stats[2][4][row] + a3 * stats[3][4][row];
            #pragma unroll
            for (int dt = 0; dt < 4; ++dt) {
                int d = dt * 16 + sl;
                float o = a0 * acc_pv[dt][r] + a1 * accPart[0][row][d]
                        + a2 * accPart[1][row][d] + a3 * accPart[2][row][d];
                o += e0 * relv_s[0][d] + e1 * relv_s[1][d] + e2 * relv_s[2][d];
                o *= linv;
                dst[(size_t)row * EMB + d] = f2bf(o);
            }
        }
    }
}

extern "C" void kernel_launch(void* const* d_in, const int* in_sizes, int n_in,
                              void* d_out, int out_size, void* d_ws, size_t ws_size,
                              hipStream_t stream) {
    int iq=0, ik=1, iv=2, irel=3, iWq=4, ibq=5, iWk=6, ibk=7, iWv=8, ibv=9, iWo=10, ibo=11, irk=12, irv=13;
    if (n_in >= 14 && in_sizes[0] == 512 * 512) {
        iWk=0; iWo=1; iWq=2; iWv=3; ibk=4; ibo=5; ibq=6; ibv=7;
        irel=8; ik=9; iq=10; irk=11; irv=12; iv=13;
    }

    const float* q_in = (const float*)d_in[iq];
    const float* k_in = (const float*)d_in[ik];
    const float* v_in = (const float*)d_in[iv];
    const int*   grel = (const int*)d_in[irel];
    const float* Wq = (const float*)d_in[iWq];
    const float* bq = (const float*)d_in[ibq];
    const float* Wk = (const float*)d_in[iWk];
    const float* bk = (const float*)d_in[ibk];
    const float* Wv = (const float*)d_in[iWv];
    const float* bv = (const float*)d_in[ibv];
    const float* Wo = (const float*)d_in[iWo];
    const float* bo = (const float*)d_in[ibo];
    const float* rk = (const float*)d_in[irk];
    const float* rv = (const float*)d_in[irv];

    unsigned short* qb  = (unsigned short*)d_ws;
    unsigned short* kb  = qb + (size_t)4096 * 512;
    unsigned short* vbT = kb + (size_t)4096 * 512;   // [b*NHEAD+h][d][s]
    unsigned short* ab  = vbT + (size_t)4096 * 512;
    unsigned short* wt  = ab + (size_t)4096 * 512;

    dim3 blk(256);
    transpose_w<<<dim3(8, 8, 4), blk, 0, stream>>>(Wq, Wk, Wv, Wo, wt);
    gemm_proj_mfma<<<dim3(8, 32, 3), blk, 0, stream>>>(q_in, k_in, v_in, wt, bq, bk, bv, qb, kb, vbT);
    attn_mfma<<<dim3(32, NHEAD, BATCH), blk, 0, stream>>>(qb, kb, vbT, grel, rk, rv, ab);
    gemm_out_mfma<<<dim3(8, 32), blk, 0, stream>>>(ab, wt + (size_t)3 * 512 * 512, bo, (float*)d_out);
}

// Round 12
// 82.959 us; speedup vs baseline: 1.1452x; 1.1452x over previous
//
#include <hip/hip_runtime.h>
#include <hip/hip_bf16.h>

#define S_LEN 512
#define EMB   512
#define NHEAD 8
#define DPH   64
#define NREL  3
#define BATCH 8

typedef __attribute__((ext_vector_type(8))) short bf16x8;
typedef __attribute__((ext_vector_type(4))) float f32x4;

__device__ __forceinline__ float bf2f(unsigned short u) {
    union { unsigned int i; float f; } cv;
    cv.i = ((unsigned int)u) << 16;
    return cv.f;
}
__device__ __forceinline__ unsigned short f2bf(float f) {
    __hip_bfloat16 h = __float2bfloat16(f);
    return *reinterpret_cast<unsigned short*>(&h);
}

// ---------------------------------------------------------------------------
// Weight transpose: Wt[z][n][k] (bf16) = W[z][k][n] (f32), z in {q,k,v,o}.
// ---------------------------------------------------------------------------
__global__ __launch_bounds__(256) void transpose_w(
    const float* __restrict__ Wq, const float* __restrict__ Wk,
    const float* __restrict__ Wv, const float* __restrict__ Wo,
    unsigned short* __restrict__ Wt)
{
    const int z = blockIdx.z;
    const float* W = (z == 0) ? Wq : (z == 1) ? Wk : (z == 2) ? Wv : Wo;
    unsigned short* dst = Wt + (size_t)z * EMB * EMB;

    __shared__ float tile[64][65];
    const int n0 = blockIdx.x * 64, k0 = blockIdx.y * 64;
    const int t = threadIdx.x;
    const int cr = t >> 4, cc = (t & 15) * 4;

    #pragma unroll
    for (int it = 0; it < 4; ++it) {
        int r = cr + it * 16;
        float4 v = *reinterpret_cast<const float4*>(W + (size_t)(k0 + r) * EMB + n0 + cc);
        tile[r][cc + 0] = v.x; tile[r][cc + 1] = v.y;
        tile[r][cc + 2] = v.z; tile[r][cc + 3] = v.w;
    }
    __syncthreads();
    #pragma unroll
    for (int it = 0; it < 4; ++it) {
        int n = cr + it * 16;
        ushort4 o;
        o.x = f2bf(tile[cc + 0][n]); o.y = f2bf(tile[cc + 1][n]);
        o.z = f2bf(tile[cc + 2][n]); o.w = f2bf(tile[cc + 3][n]);
        *reinterpret_cast<ushort4*>(dst + (size_t)(n0 + n) * EMB + k0 + cc) = o;
    }
}

// ---------------------------------------------------------------------------
// MFMA projection GEMM. 128x64 tile, 4 waves 2x2.
// z==2 (V) writes TRANSPOSED per-head: vbT[(b*NHEAD+h)*DPH + d][s] (bf16).
// ---------------------------------------------------------------------------
__global__ __launch_bounds__(256) void gemm_proj_mfma(
    const float* __restrict__ Aq, const float* __restrict__ Ak, const float* __restrict__ Av,
    const unsigned short* __restrict__ Wt,
    const float* __restrict__ bqp, const float* __restrict__ bkp, const float* __restrict__ bvp,
    unsigned short* __restrict__ oq, unsigned short* __restrict__ okp, unsigned short* __restrict__ ov)
{
    const int z = blockIdx.z;
    const float* A = (z == 0) ? Aq : (z == 1) ? Ak : Av;
    const unsigned short* W = Wt + (size_t)z * EMB * EMB;
    const float* bias = (z == 0) ? bqp : (z == 1) ? bkp : bvp;
    unsigned short* out = (z == 0) ? oq : (z == 1) ? okp : ov;

    const int n0 = blockIdx.x * 64;
    const int m0 = blockIdx.y * 128;
    const int tid = threadIdx.x;
    const int lane = tid & 63;
    const int wid = tid >> 6;
    const int wr = wid >> 1, wc = wid & 1;

    __shared__ __align__(16) unsigned char smA[128 * 64 * 2];
    __shared__ __align__(16) unsigned char smB[64 * 64 * 2];

    f32x4 acc[4][2] = {};

    for (int k0 = 0; k0 < EMB; k0 += 64) {
        __syncthreads();
        #pragma unroll
        for (int it = 0; it < 4; ++it) {
            int w = it * 256 + tid;
            int row = w >> 3, kc = w & 7;
            const float* src = A + (size_t)(m0 + row) * EMB + k0 + kc * 8;
            float4 v0 = *reinterpret_cast<const float4*>(src);
            float4 v1 = *reinterpret_cast<const float4*>(src + 4);
            union { unsigned short s[8]; uint4 u; } p;
            p.s[0] = f2bf(v0.x); p.s[1] = f2bf(v0.y); p.s[2] = f2bf(v0.z); p.s[3] = f2bf(v0.w);
            p.s[4] = f2bf(v1.x); p.s[5] = f2bf(v1.y); p.s[6] = f2bf(v1.z); p.s[7] = f2bf(v1.w);
            unsigned byte = ((unsigned)row << 7) + ((unsigned)kc << 4);
            byte ^= (unsigned)((row & 7) << 4);
            *reinterpret_cast<uint4*>(smA + byte) = p.u;
        }
        #pragma unroll
        for (int it = 0; it < 2; ++it) {
            int w = it * 256 + tid;
            int row = w >> 3, kc = w & 7;
            uint4 raw = *reinterpret_cast<const uint4*>(W + (size_t)(n0 + row) * EMB + k0 + kc * 8);
            unsigned byte = ((unsigned)row << 7) + ((unsigned)kc << 4);
            byte ^= (unsigned)((row & 7) << 4);
            *reinterpret_cast<uint4*>(smB + byte) = raw;
        }
        __syncthreads();

        #pragma unroll
        for (int ks = 0; ks < 2; ++ks) {
            bf16x8 bfrag[2];
            #pragma unroll
            for (int ni = 0; ni < 2; ++ni) {
                int col = wc * 32 + ni * 16 + (lane & 15);
                unsigned byte = ((unsigned)col << 7) + (unsigned)(ks << 6) + (unsigned)((lane >> 4) << 4);
                byte ^= (unsigned)((col & 7) << 4);
                bfrag[ni] = *reinterpret_cast<const bf16x8*>(smB + byte);
            }
            #pragma unroll
            for (int mi = 0; mi < 4; ++mi) {
                int row = wr * 64 + mi * 16 + (lane & 15);
                unsigned byte = ((unsigned)row << 7) + (unsigned)(ks << 6) + (unsigned)((lane >> 4) << 4);
                byte ^= (unsigned)((row & 7) << 4);
                bf16x8 afrag = *reinterpret_cast<const bf16x8*>(smA + byte);
                #pragma unroll
                for (int ni = 0; ni < 2; ++ni)
                    acc[mi][ni] = __builtin_amdgcn_mfma_f32_16x16x32_bf16(afrag, bfrag[ni], acc[mi][ni], 0, 0, 0);
            }
        }
    }

    if (z == 2) {
        #pragma unroll
        for (int ni = 0; ni < 2; ++ni) {
            int colg = n0 + wc * 32 + ni * 16 + (lane & 15);
            float bj = bias[colg];
            int hh = colg >> 6, dd = colg & 63;
            #pragma unroll
            for (int mi = 0; mi < 4; ++mi) {
                int rbase = m0 + wr * 64 + mi * 16 + ((lane >> 4) << 2);
                int bb = rbase >> 9, ss = rbase & 511;
                ushort4 o;
                o.x = f2bf(acc[mi][ni][0] + bj);
                o.y = f2bf(acc[mi][ni][1] + bj);
                o.z = f2bf(acc[mi][ni][2] + bj);
                o.w = f2bf(acc[mi][ni][3] + bj);
                *reinterpret_cast<ushort4*>(out + ((size_t)(bb * NHEAD + hh) * DPH + dd) * S_LEN + ss) = o;
            }
        }
    } else {
        #pragma unroll
        for (int ni = 0; ni < 2; ++ni) {
            int colg = n0 + wc * 32 + ni * 16 + (lane & 15);
            float bj = bias[colg];
            #pragma unroll
            for (int mi = 0; mi < 4; ++mi) {
                int rbase = m0 + wr * 64 + mi * 16 + ((lane >> 4) << 2);
                #pragma unroll
                for (int q = 0; q < 4; ++q)
                    out[(size_t)(rbase + q) * EMB + colg] = f2bf(acc[mi][ni][q] + bj);
            }
        }
    }
}

// ---------------------------------------------------------------------------
// MFMA output GEMM (validated round 5).
// ---------------------------------------------------------------------------
__global__ __launch_bounds__(256) void gemm_out_mfma(
    const unsigned short* __restrict__ A,
    const unsigned short* __restrict__ W,
    const float* __restrict__ bias,
    float* __restrict__ out)
{
    const int n0 = blockIdx.x * 64;
    const int m0 = blockIdx.y * 128;
    const int tid = threadIdx.x;
    const int lane = tid & 63;
    const int wid = tid >> 6;
    const int wr = wid >> 1, wc = wid & 1;

    __shared__ __align__(16) unsigned char smA[128 * 64 * 2];
    __shared__ __align__(16) unsigned char smB[64 * 64 * 2];

    f32x4 acc[4][2] = {};

    for (int k0 = 0; k0 < EMB; k0 += 64) {
        __syncthreads();
        #pragma unroll
        for (int it = 0; it < 4; ++it) {
            int w = it * 256 + tid;
            int row = w >> 3, kc = w & 7;
            uint4 raw = *reinterpret_cast<const uint4*>(A + (size_t)(m0 + row) * EMB + k0 + kc * 8);
            unsigned byte = ((unsigned)row << 7) + ((unsigned)kc << 4);
            byte ^= (unsigned)((row & 7) << 4);
            *reinterpret_cast<uint4*>(smA + byte) = raw;
        }
        #pragma unroll
        for (int it = 0; it < 2; ++it) {
            int w = it * 256 + tid;
            int row = w >> 3, kc = w & 7;
            uint4 raw = *reinterpret_cast<const uint4*>(W + (size_t)(n0 + row) * EMB + k0 + kc * 8);
            unsigned byte = ((unsigned)row << 7) + ((unsigned)kc << 4);
            byte ^= (unsigned)((row & 7) << 4);
            *reinterpret_cast<uint4*>(smB + byte) = raw;
        }
        __syncthreads();

        #pragma unroll
        for (int ks = 0; ks < 2; ++ks) {
            bf16x8 bfrag[2];
            #pragma unroll
            for (int ni = 0; ni < 2; ++ni) {
                int col = wc * 32 + ni * 16 + (lane & 15);
                unsigned byte = ((unsigned)col << 7) + (unsigned)(ks << 6) + (unsigned)((lane >> 4) << 4);
                byte ^= (unsigned)((col & 7) << 4);
                bfrag[ni] = *reinterpret_cast<const bf16x8*>(smB + byte);
            }
            #pragma unroll
            for (int mi = 0; mi < 4; ++mi) {
                int row = wr * 64 + mi * 16 + (lane & 15);
                unsigned byte = ((unsigned)row << 7) + (unsigned)(ks << 6) + (unsigned)((lane >> 4) << 4);
                byte ^= (unsigned)((row & 7) << 4);
                bf16x8 afrag = *reinterpret_cast<const bf16x8*>(smA + byte);
                #pragma unroll
                for (int ni = 0; ni < 2; ++ni)
                    acc[mi][ni] = __builtin_amdgcn_mfma_f32_16x16x32_bf16(afrag, bfrag[ni], acc[mi][ni], 0, 0, 0);
            }
        }
    }

    #pragma unroll
    for (int ni = 0; ni < 2; ++ni) {
        int colg = n0 + wc * 32 + ni * 16 + (lane & 15);
        float bj = bias[colg];
        #pragma unroll
        for (int mi = 0; mi < 4; ++mi) {
            int rbase = m0 + wr * 64 + mi * 16 + ((lane >> 4) << 2);
            #pragma unroll
            for (int q = 0; q < 4; ++q)
                out[(size_t)(rbase + q) * EMB + colg] = acc[mi][ni][q] + bj;
        }
    }
}

// ---------------------------------------------------------------------------
// Relation-aware flash attention, v6 = v4 structure + t-split across blocks.
// grid (8, NHEAD, BATCH*2): z = b*2 + thalf. Block = 512 thr = 8 waves
// (4 qstrips x 2 tgroups); tgroup covers 2 tiles of its 128-t quarter.
// Intra-block 2-group merge (v4-validated), then DUMP merged partials
// (acc bf16, stats f32) to ws. LDS: P aliases Q -> ~50 KB -> 3 blocks/CU.
// ---------------------------------------------------------------------------
__global__ __launch_bounds__(512) void attn_part(
    const unsigned short* __restrict__ qb,
    const unsigned short* __restrict__ kb,
    const unsigned short* __restrict__ vbT,
    const int* __restrict__ rel,
    const float* __restrict__ rel_k,
    unsigned short* __restrict__ accP,   // [1024][64][64] bf16
    float* __restrict__ statP)           // [1024][5][64]  (m,l,es0..2)
{
    const int s0 = blockIdx.x * 64;
    const int h  = blockIdx.y;
    const int bz = blockIdx.z;           // b*2 + thalf
    const int b  = bz >> 1;
    const int thalf = bz & 1;
    const int tid = threadIdx.x;
    const int lane = tid & 63;
    const int wid = tid >> 6;            // 0..7
    const int qstrip = wid & 3;
    const int tgroup = wid >> 2;
    const int sl = lane & 15;
    const int tg = lane >> 4;

    __shared__ __align__(16) unsigned char smQP[16384];         // Q (8KB) then P (16KB)
    __shared__ __align__(16) unsigned char smK[2 * 64 * 128];   // per t-group; accL after loop
    __shared__ __align__(16) unsigned char smVt[2 * 64 * 128];  // per t-group; stats after loop
    __shared__ float qrel_s[64][4];

    const unsigned short* qsrc  = qb + ((size_t)(b * S_LEN + s0)) * EMB + h * DPH;
    const unsigned short* ksrc  = kb + ((size_t)b * S_LEN) * EMB + h * DPH;
    const unsigned short* vsrcT = vbT + (size_t)(b * NHEAD + h) * DPH * S_LEN;

    // --- stage Q (64x64 bf16, swizzled): 512 thr x 1 uint4 ---
    {
        int row = tid >> 3, kc = tid & 7;
        uint4 raw = *reinterpret_cast<const uint4*>(qsrc + (size_t)row * EMB + kc * 8);
        unsigned byte = ((unsigned)row << 7) + ((unsigned)kc << 4);
        byte ^= (unsigned)((row & 7) << 4);
        *reinterpret_cast<uint4*>(smQP + byte) = raw;
    }
    __syncthreads();
    if (tid < 192) {
        int r = tid / 3, rr = tid - 3 * (tid / 3);
        float s = 0.f;
        #pragma unroll
        for (int dc = 0; dc < 32; ++dc) {
            unsigned byte = ((unsigned)r << 7) + (unsigned)(dc << 2);
            byte ^= (unsigned)((r & 7) << 4);
            unsigned u = *reinterpret_cast<const unsigned*>(smQP + byte);
            s += bf2f((unsigned short)(u & 0xffff)) * rel_k[rr * DPH + dc * 2]
               + bf2f((unsigned short)(u >> 16))   * rel_k[rr * DPH + dc * 2 + 1];
        }
        qrel_s[r][rr] = s;
    }
    __syncthreads();

    const int srow = qstrip * 16 + sl;
    const float qr0 = qrel_s[srow][0], qr1 = qrel_s[srow][1], qr2 = qrel_s[srow][2];

    bf16x8 qfrag[2];
    #pragma unroll
    for (int ks = 0; ks < 2; ++ks) {
        unsigned byte = ((unsigned)srow << 7) + (unsigned)(ks << 6) + (unsigned)(tg << 4);
        byte ^= (unsigned)((srow & 7) << 4);
        qfrag[ks] = *reinterpret_cast<const bf16x8*>(smQP + byte);
    }
    // NOTE: smQP's Q contents are dead from here; P region reuses it. All
    // waves' Q reads complete before their first loop barrier, and P writes
    // occur only after the loop's second barrier -> no hazard.

    const int* rrow_s = rel + ((size_t)(b * S_LEN + s0 + srow)) * S_LEN;
    const unsigned pbase = (unsigned)(wid * 2048);
    const float scale = 0.125f;

    const int gtid  = tid & 255;
    const int ldrow = gtid >> 3;
    const int ldkc  = gtid & 7;
    const unsigned wbyte0 = (((unsigned)ldrow << 7) + ((unsigned)ldkc << 4))
                            ^ ((unsigned)((ldrow & 7) << 4));
    const unsigned wbyte1 = wbyte0 + 4096;
    unsigned char* kbase = smK  + tgroup * 8192;
    unsigned char* vbase = smVt + tgroup * 8192;

    float m_run = -1e30f, l_run = 0.f;
    float es[NREL] = {};
    f32x4 acc_pv[4] = {};

    #pragma unroll
    for (int i = 0; i < 2; ++i) {
        const int t0 = thalf * 256 + tgroup * 128 + i * 64;

        uint4 k0 = *reinterpret_cast<const uint4*>(ksrc + (size_t)(t0 + ldrow) * EMB + ldkc * 8);
        uint4 k1 = *reinterpret_cast<const uint4*>(ksrc + (size_t)(t0 + ldrow + 32) * EMB + ldkc * 8);
        uint4 v0 = *reinterpret_cast<const uint4*>(vsrcT + (size_t)ldrow * S_LEN + t0 + ldkc * 8);
        uint4 v1 = *reinterpret_cast<const uint4*>(vsrcT + (size_t)(ldrow + 32) * S_LEN + t0 + ldkc * 8);
        int4 rr[4];
        #pragma unroll
        for (int t4 = 0; t4 < 4; ++t4)
            rr[t4] = *reinterpret_cast<const int4*>(rrow_s + t0 + t4 * 16 + tg * 4);

        __syncthreads();
        *reinterpret_cast<uint4*>(kbase + wbyte0) = k0;
        *reinterpret_cast<uint4*>(kbase + wbyte1) = k1;
        *reinterpret_cast<uint4*>(vbase + wbyte0) = v0;
        *reinterpret_cast<uint4*>(vbase + wbyte1) = v1;
        __syncthreads();

        f32x4 sacc[4] = {};
        #pragma unroll
        for (int ks = 0; ks < 2; ++ks)
            #pragma unroll
            for (int t4 = 0; t4 < 4; ++t4) {
                int trow = t4 * 16 + sl;
                unsigned byte = ((unsigned)trow << 7) + (unsigned)(ks << 6) + (unsigned)(tg << 4);
                byte ^= (unsigned)((trow & 7) << 4);
                bf16x8 kf = *reinterpret_cast<const bf16x8*>(kbase + byte);
                sacc[t4] = __builtin_amdgcn_mfma_f32_16x16x32_bf16(kf, qfrag[ks], sacc[t4], 0, 0, 0);
            }

        int rvv[4][4];
        float mt = -1e30f;
        #pragma unroll
        for (int t4 = 0; t4 < 4; ++t4) {
            int rv[4] = {rr[t4].x, rr[t4].y, rr[t4].z, rr[t4].w};
            #pragma unroll
            for (int j = 0; j < 4; ++j) {
                int r = rv[j]; r = r < 0 ? 0 : (r > 2 ? 2 : r);
                rvv[t4][j] = r;
                float qa = (r == 0) ? qr0 : ((r == 1) ? qr1 : qr2);
                float v = (sacc[t4][j] + qa) * scale;
                sacc[t4][j] = v;
                mt = fmaxf(mt, v);
            }
        }
        mt = fmaxf(mt, __shfl_xor(mt, 16));
        mt = fmaxf(mt, __shfl_xor(mt, 32));

        float mn = fmaxf(m_run, mt);
        float al = __expf(m_run - mn);
        m_run = mn;

        float ps = 0.f;
        #pragma unroll
        for (int t4 = 0; t4 < 4; ++t4)
            #pragma unroll
            for (int j = 0; j < 4; ++j) {
                float p = __expf(sacc[t4][j] - mn);
                sacc[t4][j] = p;
                ps += p;
            }
        float pst = ps;
        pst += __shfl_xor(pst, 16);
        pst += __shfl_xor(pst, 32);
        l_run = l_run * al + pst;

        #pragma unroll
        for (int r2 = 0; r2 < NREL; ++r2) {
            float e2 = es[r2] * al;
            #pragma unroll
            for (int t4 = 0; t4 < 4; ++t4)
                #pragma unroll
                for (int j = 0; j < 4; ++j)
                    e2 += (rvv[t4][j] == r2) ? sacc[t4][j] : 0.f;
            es[r2] = e2;
        }

        float al_s[4];
        #pragma unroll
        for (int r = 0; r < 4; ++r) al_s[r] = __shfl(al, tg * 4 + r);
        #pragma unroll
        for (int dt = 0; dt < 4; ++dt)
            #pragma unroll
            for (int r = 0; r < 4; ++r) acc_pv[dt][r] *= al_s[r];

        #pragma unroll
        for (int t4 = 0; t4 < 4; ++t4)
            #pragma unroll
            for (int pr = 0; pr < 2; ++pr) {
                unsigned u = (unsigned)f2bf(sacc[t4][2 * pr]) |
                             ((unsigned)f2bf(sacc[t4][2 * pr + 1]) << 16);
                unsigned byte = pbase + ((unsigned)sl << 7) + (unsigned)(t4 * 32 + tg * 8 + pr * 4);
                byte ^= (unsigned)((sl & 7) << 4);
                *reinterpret_cast<unsigned*>(smQP + byte) = u;
            }

        #pragma unroll
        for (int ks = 0; ks < 2; ++ks) {
            unsigned pbyte = pbase + ((unsigned)sl << 7) + (unsigned)(ks << 6) + (unsigned)(tg << 4);
            pbyte ^= (unsigned)((sl & 7) << 4);
            bf16x8 pf = *reinterpret_cast<const bf16x8*>(smQP + pbyte);
            #pragma unroll
            for (int dt = 0; dt < 4; ++dt) {
                int d = dt * 16 + sl;
                unsigned vbyte = ((unsigned)d << 7) + (unsigned)(ks << 6) + (unsigned)(tg << 4);
                vbyte ^= (unsigned)((d & 7) << 4);
                bf16x8 vf = *reinterpret_cast<const bf16x8*>(vbase + vbyte);
                acc_pv[dt] = __builtin_amdgcn_mfma_f32_16x16x32_bf16(pf, vf, acc_pv[dt], 0, 0, 0);
            }
        }
    }

    // es cross-reduce within group
    #pragma unroll
    for (int r2 = 0; r2 < NREL; ++r2) {
        es[r2] += __shfl_xor(es[r2], 16);
        es[r2] += __shfl_xor(es[r2], 32);
    }

    // ---- intra-block merge of the 2 t-groups (v4-validated), then dump ----
    __syncthreads();
    float* accL  = reinterpret_cast<float*>(smK);    // [64][64]
    float* stats = reinterpret_cast<float*>(smVt);   // m[2][64], l[2][64], es[2][3][64]

    if (tg == 0) {
        stats[tgroup * 64 + srow]        = m_run;
        stats[128 + tgroup * 64 + srow]  = l_run;
        #pragma unroll
        for (int r2 = 0; r2 < NREL; ++r2)
            stats[256 + (tgroup * 3 + r2) * 64 + srow] = es[r2];
    }
    if (tgroup == 1) {
        #pragma unroll
        for (int dt = 0; dt < 4; ++dt)
            #pragma unroll
            for (int r = 0; r < 4; ++r)
                accL[(qstrip * 16 + tg * 4 + r) * 64 + dt * 16 + sl] = acc_pv[dt][r];
    }
    __syncthreads();

    if (tgroup == 0) {
        const size_t pidx = ((size_t)bz * 8 + blockIdx.x) * NHEAD + h;
        unsigned short* accD = accP + pidx * 4096;
        float* statD = statP + pidx * 320;
        #pragma unroll
        for (int r = 0; r < 4; ++r) {
            const int row64 = qstrip * 16 + tg * 4 + r;
            float m0 = stats[row64],        m1 = stats[64 + row64];
            float l0 = stats[128 + row64],  l1 = stats[192 + row64];
            float mm = fmaxf(m0, m1);
            float a0 = __expf(m0 - mm), a1 = __expf(m1 - mm);
            float lm = a0 * l0 + a1 * l1;
            #pragma unroll
            for (int dt = 0; dt < 4; ++dt) {
                int d = dt * 16 + sl;
                float v = a0 * acc_pv[dt][r] + a1 * accL[row64 * 64 + d];
                accD[row64 * 64 + d] = f2bf(v);
            }
            if (sl == 0) {
                statD[row64]       = mm;
                statD[64 + row64]  = lm;
                #pragma unroll
                for (int r2 = 0; r2 < NREL; ++r2)
                    statD[128 + r2 * 64 + row64] =
                        a0 * stats[256 + r2 * 64 + row64] + a1 * stats[256 + (3 + r2) * 64 + row64];
            }
        }
    }
}

// ---------------------------------------------------------------------------
// Merge the two t-halves: flash combine + es.rel_v + 1/l -> ab (bf16).
// grid (8, 64): (sblk, b*NHEAD+h). 256 threads.
// ---------------------------------------------------------------------------
__global__ __launch_bounds__(256) void attn_merge(
    const unsigned short* __restrict__ accP,
    const float* __restrict__ statP,
    const float* __restrict__ rel_v,
    unsigned short* __restrict__ ab)
{
    const int sblk = blockIdx.x;
    const int bh = blockIdx.y;
    const int b = bh >> 3, h = bh & 7;
    const int tid = threadIdx.x;

    const size_t p0 = (((size_t)(b * 2 + 0) * 8 + sblk)) * NHEAD + h;
    const size_t p1 = p0 + 64;   // thalf=1 adds 8*NHEAD

    __shared__ float w0[64], w1[64], e0s[64], e1s[64], e2s[64], li[64];
    __shared__ float relv_s[NREL][64];

    if (tid < 64) {
        int row = tid;
        float m0 = statP[p0 * 320 + row], m1 = statP[p1 * 320 + row];
        float l0 = statP[p0 * 320 + 64 + row], l1 = statP[p1 * 320 + 64 + row];
        float mm = fmaxf(m0, m1);
        float a0 = __expf(m0 - mm), a1 = __expf(m1 - mm);
        w0[row] = a0; w1[row] = a1;
        li[row] = 1.f / (a0 * l0 + a1 * l1);
        e0s[row] = a0 * statP[p0 * 320 + 128 + row] + a1 * statP[p1 * 320 + 128 + row];
        e1s[row] = a0 * statP[p0 * 320 + 192 + row] + a1 * statP[p1 * 320 + 192 + row];
        e2s[row] = a0 * statP[p0 * 320 + 256 + row] + a1 * statP[p1 * 320 + 256 + row];
    }
    if (tid < NREL * 64) {
        int rr = tid >> 6, d = tid & 63;
        relv_s[rr][d] = rel_v[rr * DPH + d];
    }
    __syncthreads();

    const unsigned short* a0p = accP + p0 * 4096;
    const unsigned short* a1p = accP + p1 * 4096;
    unsigned short* dst = ab + ((size_t)(b * S_LEN + sblk * 64)) * EMB + h * DPH;

    #pragma unroll
    for (int it = 0; it < 16; ++it) {
        int idx = it * 256 + tid;
        int row = idx >> 6, d = idx & 63;
        float v = w0[row] * bf2f(a0p[idx]) + w1[row] * bf2f(a1p[idx]);
        v += e0s[row] * relv_s[0][d] + e1s[row] * relv_s[1][d] + e2s[row] * relv_s[2][d];
        v *= li[row];
        dst[(size_t)row * EMB + d] = f2bf(v);
    }
}

extern "C" void kernel_launch(void* const* d_in, const int* in_sizes, int n_in,
                              void* d_out, int out_size, void* d_ws, size_t ws_size,
                              hipStream_t stream) {
    int iq=0, ik=1, iv=2, irel=3, iWq=4, ibq=5, iWk=6, ibk=7, iWv=8, ibv=9, iWo=10, ibo=11, irk=12, irv=13;
    if (n_in >= 14 && in_sizes[0] == 512 * 512) {
        iWk=0; iWo=1; iWq=2; iWv=3; ibk=4; ibo=5; ibq=6; ibv=7;
        irel=8; ik=9; iq=10; irk=11; irv=12; iv=13;
    }

    const float* q_in = (const float*)d_in[iq];
    const float* k_in = (const float*)d_in[ik];
    const float* v_in = (const float*)d_in[iv];
    const int*   grel = (const int*)d_in[irel];
    const float* Wq = (const float*)d_in[iWq];
    const float* bq = (const float*)d_in[ibq];
    const float* Wk = (const float*)d_in[iWk];
    const float* bk = (const float*)d_in[ibk];
    const float* Wv = (const float*)d_in[iWv];
    const float* bv = (const float*)d_in[ibv];
    const float* Wo = (const float*)d_in[iWo];
    const float* bo = (const float*)d_in[ibo];
    const float* rk = (const float*)d_in[irk];
    const float* rv = (const float*)d_in[irv];

    // ws layout (bytes):
    //   qb 4MB | kb 4MB | vbT 4MB | ab 4MB | wt 2MB | accP 8MB | statP 1.25MB
    unsigned short* qb  = (unsigned short*)d_ws;
    unsigned short* kb  = qb + (size_t)4096 * 512;
    unsigned short* vbT = kb + (size_t)4096 * 512;
    unsigned short* ab  = vbT + (size_t)4096 * 512;
    unsigned short* wt  = ab + (size_t)4096 * 512;
    unsigned short* accP = wt + (size_t)4 * 512 * 512;
    float* statP = (float*)(accP + (size_t)1024 * 4096);

    dim3 blk(256);
    transpose_w<<<dim3(8, 8, 4), blk, 0, stream>>>(Wq, Wk, Wv, Wo, wt);
    gemm_proj_mfma<<<dim3(8, 32, 3), blk, 0, stream>>>(q_in, k_in, v_in, wt, bq, bk, bv, qb, kb, vbT);
    attn_part<<<dim3(8, NHEAD, BATCH * 2), dim3(512), 0, stream>>>(qb, kb, vbT, grel, rk, accP, statP);
    attn_merge<<<dim3(8, NHEAD * BATCH), blk, 0, stream>>>(accP, statP, rv, ab);
    gemm_out_mfma<<<dim3(8, 32), blk, 0, stream>>>(ab, wt + (size_t)3 * 512 * 512, bo, (float*)d_out);
}

// Round 13
// 80.285 us; speedup vs baseline: 1.1833x; 1.0333x over previous
//
#include <hip/hip_runtime.h>
#include <hip/hip_bf16.h>

#define S_LEN 512
#define EMB   512
#define NHEAD 8
#define DPH   64
#define NREL  3
#define BATCH 8

typedef __attribute__((ext_vector_type(8))) short bf16x8;
typedef __attribute__((ext_vector_type(4))) float f32x4;

__device__ __forceinline__ float bf2f(unsigned short u) {
    union { unsigned int i; float f; } cv;
    cv.i = ((unsigned int)u) << 16;
    return cv.f;
}
__device__ __forceinline__ unsigned short f2bf(float f) {
    __hip_bfloat16 h = __float2bfloat16(f);
    return *reinterpret_cast<unsigned short*>(&h);
}

// ---------------------------------------------------------------------------
// Weight transpose: Wt[z][n][k] (bf16) = W[z][k][n] (f32), z in {q,k,v,o}.
// ---------------------------------------------------------------------------
__global__ __launch_bounds__(256) void transpose_w(
    const float* __restrict__ Wq, const float* __restrict__ Wk,
    const float* __restrict__ Wv, const float* __restrict__ Wo,
    unsigned short* __restrict__ Wt)
{
    const int z = blockIdx.z;
    const float* W = (z == 0) ? Wq : (z == 1) ? Wk : (z == 2) ? Wv : Wo;
    unsigned short* dst = Wt + (size_t)z * EMB * EMB;

    __shared__ float tile[64][65];
    const int n0 = blockIdx.x * 64, k0 = blockIdx.y * 64;
    const int t = threadIdx.x;
    const int cr = t >> 4, cc = (t & 15) * 4;

    #pragma unroll
    for (int it = 0; it < 4; ++it) {
        int r = cr + it * 16;
        float4 v = *reinterpret_cast<const float4*>(W + (size_t)(k0 + r) * EMB + n0 + cc);
        tile[r][cc + 0] = v.x; tile[r][cc + 1] = v.y;
        tile[r][cc + 2] = v.z; tile[r][cc + 3] = v.w;
    }
    __syncthreads();
    #pragma unroll
    for (int it = 0; it < 4; ++it) {
        int n = cr + it * 16;
        ushort4 o;
        o.x = f2bf(tile[cc + 0][n]); o.y = f2bf(tile[cc + 1][n]);
        o.z = f2bf(tile[cc + 2][n]); o.w = f2bf(tile[cc + 3][n]);
        *reinterpret_cast<ushort4*>(dst + (size_t)(n0 + n) * EMB + k0 + cc) = o;
    }
}

// ---------------------------------------------------------------------------
// MFMA projection GEMM. 128x64 tile, 4 waves 2x2.
// z==2 (V) writes TRANSPOSED per-head: vbT[(b*NHEAD+h)*DPH + d][s] (bf16).
// ---------------------------------------------------------------------------
__global__ __launch_bounds__(256) void gemm_proj_mfma(
    const float* __restrict__ Aq, const float* __restrict__ Ak, const float* __restrict__ Av,
    const unsigned short* __restrict__ Wt,
    const float* __restrict__ bqp, const float* __restrict__ bkp, const float* __restrict__ bvp,
    unsigned short* __restrict__ oq, unsigned short* __restrict__ okp, unsigned short* __restrict__ ov)
{
    const int z = blockIdx.z;
    const float* A = (z == 0) ? Aq : (z == 1) ? Ak : Av;
    const unsigned short* W = Wt + (size_t)z * EMB * EMB;
    const float* bias = (z == 0) ? bqp : (z == 1) ? bkp : bvp;
    unsigned short* out = (z == 0) ? oq : (z == 1) ? okp : ov;

    const int n0 = blockIdx.x * 64;
    const int m0 = blockIdx.y * 128;
    const int tid = threadIdx.x;
    const int lane = tid & 63;
    const int wid = tid >> 6;
    const int wr = wid >> 1, wc = wid & 1;

    __shared__ __align__(16) unsigned char smA[128 * 64 * 2];
    __shared__ __align__(16) unsigned char smB[64 * 64 * 2];

    f32x4 acc[4][2] = {};

    for (int k0 = 0; k0 < EMB; k0 += 64) {
        __syncthreads();
        #pragma unroll
        for (int it = 0; it < 4; ++it) {
            int w = it * 256 + tid;
            int row = w >> 3, kc = w & 7;
            const float* src = A + (size_t)(m0 + row) * EMB + k0 + kc * 8;
            float4 v0 = *reinterpret_cast<const float4*>(src);
            float4 v1 = *reinterpret_cast<const float4*>(src + 4);
            union { unsigned short s[8]; uint4 u; } p;
            p.s[0] = f2bf(v0.x); p.s[1] = f2bf(v0.y); p.s[2] = f2bf(v0.z); p.s[3] = f2bf(v0.w);
            p.s[4] = f2bf(v1.x); p.s[5] = f2bf(v1.y); p.s[6] = f2bf(v1.z); p.s[7] = f2bf(v1.w);
            unsigned byte = ((unsigned)row << 7) + ((unsigned)kc << 4);
            byte ^= (unsigned)((row & 7) << 4);
            *reinterpret_cast<uint4*>(smA + byte) = p.u;
        }
        #pragma unroll
        for (int it = 0; it < 2; ++it) {
            int w = it * 256 + tid;
            int row = w >> 3, kc = w & 7;
            uint4 raw = *reinterpret_cast<const uint4*>(W + (size_t)(n0 + row) * EMB + k0 + kc * 8);
            unsigned byte = ((unsigned)row << 7) + ((unsigned)kc << 4);
            byte ^= (unsigned)((row & 7) << 4);
            *reinterpret_cast<uint4*>(smB + byte) = raw;
        }
        __syncthreads();

        #pragma unroll
        for (int ks = 0; ks < 2; ++ks) {
            bf16x8 bfrag[2];
            #pragma unroll
            for (int ni = 0; ni < 2; ++ni) {
                int col = wc * 32 + ni * 16 + (lane & 15);
                unsigned byte = ((unsigned)col << 7) + (unsigned)(ks << 6) + (unsigned)((lane >> 4) << 4);
                byte ^= (unsigned)((col & 7) << 4);
                bfrag[ni] = *reinterpret_cast<const bf16x8*>(smB + byte);
            }
            #pragma unroll
            for (int mi = 0; mi < 4; ++mi) {
                int row = wr * 64 + mi * 16 + (lane & 15);
                unsigned byte = ((unsigned)row << 7) + (unsigned)(ks << 6) + (unsigned)((lane >> 4) << 4);
                byte ^= (unsigned)((row & 7) << 4);
                bf16x8 afrag = *reinterpret_cast<const bf16x8*>(smA + byte);
                #pragma unroll
                for (int ni = 0; ni < 2; ++ni)
                    acc[mi][ni] = __builtin_amdgcn_mfma_f32_16x16x32_bf16(afrag, bfrag[ni], acc[mi][ni], 0, 0, 0);
            }
        }
    }

    if (z == 2) {
        #pragma unroll
        for (int ni = 0; ni < 2; ++ni) {
            int colg = n0 + wc * 32 + ni * 16 + (lane & 15);
            float bj = bias[colg];
            int hh = colg >> 6, dd = colg & 63;
            #pragma unroll
            for (int mi = 0; mi < 4; ++mi) {
                int rbase = m0 + wr * 64 + mi * 16 + ((lane >> 4) << 2);
                int bb = rbase >> 9, ss = rbase & 511;
                ushort4 o;
                o.x = f2bf(acc[mi][ni][0] + bj);
                o.y = f2bf(acc[mi][ni][1] + bj);
                o.z = f2bf(acc[mi][ni][2] + bj);
                o.w = f2bf(acc[mi][ni][3] + bj);
                *reinterpret_cast<ushort4*>(out + ((size_t)(bb * NHEAD + hh) * DPH + dd) * S_LEN + ss) = o;
            }
        }
    } else {
        #pragma unroll
        for (int ni = 0; ni < 2; ++ni) {
            int colg = n0 + wc * 32 + ni * 16 + (lane & 15);
            float bj = bias[colg];
            #pragma unroll
            for (int mi = 0; mi < 4; ++mi) {
                int rbase = m0 + wr * 64 + mi * 16 + ((lane >> 4) << 2);
                #pragma unroll
                for (int q = 0; q < 4; ++q)
                    out[(size_t)(rbase + q) * EMB + colg] = f2bf(acc[mi][ni][q] + bj);
            }
        }
    }
}

// ---------------------------------------------------------------------------
// MFMA output GEMM (validated round 5).
// ---------------------------------------------------------------------------
__global__ __launch_bounds__(256) void gemm_out_mfma(
    const unsigned short* __restrict__ A,
    const unsigned short* __restrict__ W,
    const float* __restrict__ bias,
    float* __restrict__ out)
{
    const int n0 = blockIdx.x * 64;
    const int m0 = blockIdx.y * 128;
    const int tid = threadIdx.x;
    const int lane = tid & 63;
    const int wid = tid >> 6;
    const int wr = wid >> 1, wc = wid & 1;

    __shared__ __align__(16) unsigned char smA[128 * 64 * 2];
    __shared__ __align__(16) unsigned char smB[64 * 64 * 2];

    f32x4 acc[4][2] = {};

    for (int k0 = 0; k0 < EMB; k0 += 64) {
        __syncthreads();
        #pragma unroll
        for (int it = 0; it < 4; ++it) {
            int w = it * 256 + tid;
            int row = w >> 3, kc = w & 7;
            uint4 raw = *reinterpret_cast<const uint4*>(A + (size_t)(m0 + row) * EMB + k0 + kc * 8);
            unsigned byte = ((unsigned)row << 7) + ((unsigned)kc << 4);
            byte ^= (unsigned)((row & 7) << 4);
            *reinterpret_cast<uint4*>(smA + byte) = raw;
        }
        #pragma unroll
        for (int it = 0; it < 2; ++it) {
            int w = it * 256 + tid;
            int row = w >> 3, kc = w & 7;
            uint4 raw = *reinterpret_cast<const uint4*>(W + (size_t)(n0 + row) * EMB + k0 + kc * 8);
            unsigned byte = ((unsigned)row << 7) + ((unsigned)kc << 4);
            byte ^= (unsigned)((row & 7) << 4);
            *reinterpret_cast<uint4*>(smB + byte) = raw;
        }
        __syncthreads();

        #pragma unroll
        for (int ks = 0; ks < 2; ++ks) {
            bf16x8 bfrag[2];
            #pragma unroll
            for (int ni = 0; ni < 2; ++ni) {
                int col = wc * 32 + ni * 16 + (lane & 15);
                unsigned byte = ((unsigned)col << 7) + (unsigned)(ks << 6) + (unsigned)((lane >> 4) << 4);
                byte ^= (unsigned)((col & 7) << 4);
                bfrag[ni] = *reinterpret_cast<const bf16x8*>(smB + byte);
            }
            #pragma unroll
            for (int mi = 0; mi < 4; ++mi) {
                int row = wr * 64 + mi * 16 + (lane & 15);
                unsigned byte = ((unsigned)row << 7) + (unsigned)(ks << 6) + (unsigned)((lane >> 4) << 4);
                byte ^= (unsigned)((row & 7) << 4);
                bf16x8 afrag = *reinterpret_cast<const bf16x8*>(smA + byte);
                #pragma unroll
                for (int ni = 0; ni < 2; ++ni)
                    acc[mi][ni] = __builtin_amdgcn_mfma_f32_16x16x32_bf16(afrag, bfrag[ni], acc[mi][ni], 0, 0, 0);
            }
        }
    }

    #pragma unroll
    for (int ni = 0; ni < 2; ++ni) {
        int colg = n0 + wc * 32 + ni * 16 + (lane & 15);
        float bj = bias[colg];
        #pragma unroll
        for (int mi = 0; mi < 4; ++mi) {
            int rbase = m0 + wr * 64 + mi * 16 + ((lane >> 4) << 2);
            #pragma unroll
            for (int q = 0; q < 4; ++q)
                out[(size_t)(rbase + q) * EMB + colg] = acc[mi][ni][q] + bj;
        }
    }
}

// ---------------------------------------------------------------------------
// Relation-aware attention, v7: wave-private staging, ZERO loop barriers,
// no-max softmax (P = exp(s-8), exact after /l), end-only cross-lane reduce.
// Block = 256 thr = 4 waves; block owns 16 q-rows; wave w owns t-quarter
// [w*128, w*128+128) as 4 tiles of 32 t, staged in wave-private LDS.
// Epilogue: 4-way sum-merge via LDS (weights all 1), one barrier.
// grid (32, NHEAD, BATCH) = 2048 blocks; LDS ~36 KB -> 4 blocks/CU.
// ---------------------------------------------------------------------------
__global__ __launch_bounds__(256, 4) void attn_mfma(
    const unsigned short* __restrict__ qb,
    const unsigned short* __restrict__ kb,
    const unsigned short* __restrict__ vbT,
    const int* __restrict__ rel,
    const float* __restrict__ rel_k, const float* __restrict__ rel_v,
    unsigned short* __restrict__ ob)
{
    const int s0 = blockIdx.x * 16;
    const int h  = blockIdx.y;
    const int b  = blockIdx.z;
    const int tid = threadIdx.x;
    const int lane = tid & 63;
    const int wid = tid >> 6;          // t-quarter 0..3
    const int sl = lane & 15;
    const int tg = lane >> 4;

    __shared__ __align__(16) unsigned char smKV[4][8192];  // per-wave K(4KB)+V(4KB); merge scratch after loop
    __shared__ __align__(16) unsigned char smP[4][1024];   // per-wave P (16x32 bf16)
    __shared__ __align__(16) unsigned char smQ[2048];      // 16x64 bf16 swizzled
    __shared__ float qrel_s[16][4];
    __shared__ float relv_s[NREL][64];

    const unsigned short* qsrc  = qb + ((size_t)(b * S_LEN + s0)) * EMB + h * DPH;
    const unsigned short* ksrc  = kb + ((size_t)b * S_LEN) * EMB + h * DPH;
    const unsigned short* vsrcT = vbT + (size_t)(b * NHEAD + h) * DPH * S_LEN;

    // --- stage Q (16x64 bf16, swizzled): 128 x uint4 ---
    if (tid < 128) {
        int row = tid >> 3, kc = tid & 7;
        uint4 raw = *reinterpret_cast<const uint4*>(qsrc + (size_t)row * EMB + kc * 8);
        unsigned byte = ((unsigned)row << 7) + ((unsigned)kc << 4);
        byte ^= (unsigned)((row & 7) << 4);
        *reinterpret_cast<uint4*>(smQ + byte) = raw;
    }
    if (tid < NREL * 64) {
        int rr = tid >> 6, d = tid & 63;
        relv_s[rr][d] = rel_v[rr * DPH + d];
    }
    __syncthreads();
    if (tid < 48) {
        int r = tid / 3, rr = tid - 3 * (tid / 3);
        float s = 0.f;
        #pragma unroll
        for (int dc = 0; dc < 32; ++dc) {
            unsigned byte = ((unsigned)r << 7) + (unsigned)(dc << 2);
            byte ^= (unsigned)((r & 7) << 4);
            unsigned u = *reinterpret_cast<const unsigned*>(smQ + byte);
            s += bf2f((unsigned short)(u & 0xffff)) * rel_k[rr * DPH + dc * 2]
               + bf2f((unsigned short)(u >> 16))   * rel_k[rr * DPH + dc * 2 + 1];
        }
        qrel_s[r][rr] = s;
    }
    __syncthreads();

    const float qr0 = qrel_s[sl][0], qr1 = qrel_s[sl][1], qr2 = qrel_s[sl][2];

    bf16x8 qfrag[2];
    #pragma unroll
    for (int ks = 0; ks < 2; ++ks) {
        unsigned byte = ((unsigned)sl << 7) + (unsigned)(ks << 6) + (unsigned)(tg << 4);
        byte ^= (unsigned)((sl & 7) << 4);
        qfrag[ks] = *reinterpret_cast<const bf16x8*>(smQ + byte);
    }

    const int* rrow_s = rel + ((size_t)(b * S_LEN + s0 + sl)) * S_LEN;
    const float scale = 0.125f;

    unsigned char* kbase = smKV[wid];
    unsigned char* vbase = smKV[wid] + 4096;
    unsigned char* pbase = smP[wid];

    float l_run = 0.f, es1 = 0.f, es2 = 0.f;
    f32x4 acc_pv[4] = {};

    // ---- main loop: 4 tiles of 32 t, wave-private, NO barriers ----
    #pragma unroll 1
    for (int i = 0; i < 4; ++i) {
        const int t0 = wid * 128 + i * 32;

        // stage K [32 t][64 d] and V^T [64 d][32 t] into private LDS
        #pragma unroll
        for (int it = 0; it < 4; ++it) {
            int ck = it * 64 + lane;
            int krow = ck >> 3, kc = ck & 7;
            uint4 kv = *reinterpret_cast<const uint4*>(ksrc + (size_t)(t0 + krow) * EMB + kc * 8);
            unsigned kbyte = ((unsigned)krow << 7) + ((unsigned)kc << 4);
            kbyte ^= (unsigned)((krow & 7) << 4);
            *reinterpret_cast<uint4*>(kbase + kbyte) = kv;
            int dv = ck >> 2, tc = ck & 3;
            uint4 vv = *reinterpret_cast<const uint4*>(vsrcT + (size_t)dv * S_LEN + t0 + tc * 8);
            unsigned vbyte = ((unsigned)dv << 6) + ((unsigned)tc << 4);
            vbyte ^= (unsigned)((dv & 3) << 4);
            *reinterpret_cast<uint4*>(vbase + vbyte) = vv;
        }

        // QK^T: C[t][s], 2 t-subtiles x 2 k-halves
        f32x4 sacc[2] = {};
        #pragma unroll
        for (int ks = 0; ks < 2; ++ks)
            #pragma unroll
            for (int t4 = 0; t4 < 2; ++t4) {
                int trow = t4 * 16 + sl;
                unsigned byte = ((unsigned)trow << 7) + (unsigned)((ks * 4 + tg) << 4);
                byte ^= (unsigned)((trow & 7) << 4);
                bf16x8 kf = *reinterpret_cast<const bf16x8*>(kbase + byte);
                sacc[t4] = __builtin_amdgcn_mfma_f32_16x16x32_bf16(kf, qfrag[ks], sacc[t4], 0, 0, 0);
            }

        // rel + no-max softmax: P = exp((qk+qa)*scale - 8)
        #pragma unroll
        for (int t4 = 0; t4 < 2; ++t4) {
            int4 rr = *reinterpret_cast<const int4*>(rrow_s + t0 + t4 * 16 + tg * 4);
            int rv[4] = {rr.x, rr.y, rr.z, rr.w};
            #pragma unroll
            for (int j = 0; j < 4; ++j) {
                int r = rv[j]; r = r < 0 ? 0 : (r > 2 ? 2 : r);
                float qa = (r == 0) ? qr0 : ((r == 1) ? qr1 : qr2);
                float p = __expf((sacc[t4][j] + qa) * scale - 8.f);
                sacc[t4][j] = p;
                l_run += p;
                es1 += (r == 1) ? p : 0.f;
                es2 += (r == 2) ? p : 0.f;
            }
        }

        // P -> private LDS (bf16, swizzled 64B rows); same-wave, in-order
        #pragma unroll
        for (int t4 = 0; t4 < 2; ++t4) {
            uint2 u2;
            u2.x = (unsigned)f2bf(sacc[t4][0]) | ((unsigned)f2bf(sacc[t4][1]) << 16);
            u2.y = (unsigned)f2bf(sacc[t4][2]) | ((unsigned)f2bf(sacc[t4][3]) << 16);
            unsigned byte = ((unsigned)sl << 6) + (unsigned)(t4 * 32 + tg * 8);
            byte ^= (unsigned)((sl & 3) << 4);
            *reinterpret_cast<uint2*>(pbase + byte) = u2;
        }

        // PV: acc[s][d] += P[s][t] V[t][d]  (K-dim = 32, single ks)
        unsigned pbyte = ((unsigned)sl << 6) + (unsigned)(tg << 4);
        pbyte ^= (unsigned)((sl & 3) << 4);
        bf16x8 pf = *reinterpret_cast<const bf16x8*>(pbase + pbyte);
        #pragma unroll
        for (int dt = 0; dt < 4; ++dt) {
            int drow = dt * 16 + sl;
            unsigned vbyte = ((unsigned)drow << 6) + (unsigned)(tg << 4);
            vbyte ^= (unsigned)((drow & 3) << 4);
            bf16x8 vf = *reinterpret_cast<const bf16x8*>(vbase + vbyte);
            acc_pv[dt] = __builtin_amdgcn_mfma_f32_16x16x32_bf16(pf, vf, acc_pv[dt], 0, 0, 0);
        }
    }

    // end-only cross-lane reduce: full row sums over this wave's 128 t
    l_run += __shfl_xor(l_run, 16);  l_run += __shfl_xor(l_run, 32);
    es1   += __shfl_xor(es1, 16);    es1   += __shfl_xor(es1, 32);
    es2   += __shfl_xor(es2, 16);    es2   += __shfl_xor(es2, 32);

    // ---- publish partials (waves 1..3) into own KV region; merge by wave 0 ----
    if (wid > 0) {
        float* accW = reinterpret_cast<float*>(smKV[wid]);          // [16][64]
        float* stW  = reinterpret_cast<float*>(smKV[wid] + 4096);   // l[16], es1[16], es2[16]
        #pragma unroll
        for (int dt = 0; dt < 4; ++dt)
            #pragma unroll
            for (int r = 0; r < 4; ++r)
                accW[(tg * 4 + r) * 64 + dt * 16 + sl] = acc_pv[dt][r];
        if (tg == 0) {
            stW[sl]      = l_run;
            stW[16 + sl] = es1;
            stW[32 + sl] = es2;
        }
    }
    __syncthreads();

    if (wid == 0) {
        unsigned short* dst = ob + ((size_t)(b * S_LEN + s0)) * EMB + h * DPH;
        #pragma unroll
        for (int r = 0; r < 4; ++r) {
            const int row = tg * 4 + r;
            float lt  = __shfl(l_run, row);
            float e1t = __shfl(es1, row);
            float e2t = __shfl(es2, row);
            #pragma unroll
            for (int w = 1; w < 4; ++w) {
                const float* stW = reinterpret_cast<const float*>(smKV[w] + 4096);
                lt  += stW[row];
                e1t += stW[16 + row];
                e2t += stW[32 + row];
            }
            float e0t = lt - e1t - e2t;
            float linv = 1.f / lt;
            #pragma unroll
            for (int dt = 0; dt < 4; ++dt) {
                int d = dt * 16 + sl;
                float o = acc_pv[dt][r];
                #pragma unroll
                for (int w = 1; w < 4; ++w)
                    o += reinterpret_cast<const float*>(smKV[w])[row * 64 + d];
                o += e0t * relv_s[0][d] + e1t * relv_s[1][d] + e2t * relv_s[2][d];
                o *= linv;
                dst[(size_t)row * EMB + d] = f2bf(o);
            }
        }
    }
}

extern "C" void kernel_launch(void* const* d_in, const int* in_sizes, int n_in,
                              void* d_out, int out_size, void* d_ws, size_t ws_size,
                              hipStream_t stream) {
    int iq=0, ik=1, iv=2, irel=3, iWq=4, ibq=5, iWk=6, ibk=7, iWv=8, ibv=9, iWo=10, ibo=11, irk=12, irv=13;
    if (n_in >= 14 && in_sizes[0] == 512 * 512) {
        iWk=0; iWo=1; iWq=2; iWv=3; ibk=4; ibo=5; ibq=6; ibv=7;
        irel=8; ik=9; iq=10; irk=11; irv=12; iv=13;
    }

    const float* q_in = (const float*)d_in[iq];
    const float* k_in = (const float*)d_in[ik];
    const float* v_in = (const float*)d_in[iv];
    const int*   grel = (const int*)d_in[irel];
    const float* Wq = (const float*)d_in[iWq];
    const float* bq = (const float*)d_in[ibq];
    const float* Wk = (const float*)d_in[iWk];
    const float* bk = (const float*)d_in[ibk];
    const float* Wv = (const float*)d_in[iWv];
    const float* bv = (const float*)d_in[ibv];
    const float* Wo = (const float*)d_in[iWo];
    const float* bo = (const float*)d_in[ibo];
    const float* rk = (const float*)d_in[irk];
    const float* rv = (const float*)d_in[irv];

    unsigned short* qb  = (unsigned short*)d_ws;
    unsigned short* kb  = qb + (size_t)4096 * 512;
    unsigned short* vbT = kb + (size_t)4096 * 512;   // [b*NHEAD+h][d][s]
    unsigned short* ab  = vbT + (size_t)4096 * 512;
    unsigned short* wt  = ab + (size_t)4096 * 512;

    dim3 blk(256);
    transpose_w<<<dim3(8, 8, 4), blk, 0, stream>>>(Wq, Wk, Wv, Wo, wt);
    gemm_proj_mfma<<<dim3(8, 32, 3), blk, 0, stream>>>(q_in, k_in, v_in, wt, bq, bk, bv, qb, kb, vbT);
    attn_mfma<<<dim3(32, NHEAD, BATCH), blk, 0, stream>>>(qb, kb, vbT, grel, rk, rv, ab);
    gemm_out_mfma<<<dim3(8, 32), blk, 0, stream>>>(ab, wt + (size_t)3 * 512 * 512, bo, (float*)d_out);
}

// Round 15
// 70.378 us; speedup vs baseline: 1.3499x; 1.1408x over previous
//
#include <hip/hip_runtime.h>
#include <hip/hip_bf16.h>

#define S_LEN 512
#define EMB   512
#define NHEAD 8
#define DPH   64
#define NREL  3
#define BATCH 8

typedef __attribute__((ext_vector_type(8))) short bf16x8;
typedef __attribute__((ext_vector_type(4))) float f32x4;

__device__ __forceinline__ float bf2f(unsigned short u) {
    union { unsigned int i; float f; } cv;
    cv.i = ((unsigned int)u) << 16;
    return cv.f;
}
__device__ __forceinline__ unsigned short f2bf(float f) {
    __hip_bfloat16 h = __float2bfloat16(f);
    return *reinterpret_cast<unsigned short*>(&h);
}

// ---------------------------------------------------------------------------
// Weight transpose: Wt[z][n][k] (bf16) = W[z][k][n] (f32), z in {q,k,v,o}.
// ---------------------------------------------------------------------------
__global__ __launch_bounds__(256) void transpose_w(
    const float* __restrict__ Wq, const float* __restrict__ Wk,
    const float* __restrict__ Wv, const float* __restrict__ Wo,
    unsigned short* __restrict__ Wt)
{
    const int z = blockIdx.z;
    const float* W = (z == 0) ? Wq : (z == 1) ? Wk : (z == 2) ? Wv : Wo;
    unsigned short* dst = Wt + (size_t)z * EMB * EMB;

    __shared__ float tile[64][65];
    const int n0 = blockIdx.x * 64, k0 = blockIdx.y * 64;
    const int t = threadIdx.x;
    const int cr = t >> 4, cc = (t & 15) * 4;

    #pragma unroll
    for (int it = 0; it < 4; ++it) {
        int r = cr + it * 16;
        float4 v = *reinterpret_cast<const float4*>(W + (size_t)(k0 + r) * EMB + n0 + cc);
        tile[r][cc + 0] = v.x; tile[r][cc + 1] = v.y;
        tile[r][cc + 2] = v.z; tile[r][cc + 3] = v.w;
    }
    __syncthreads();
    #pragma unroll
    for (int it = 0; it < 4; ++it) {
        int n = cr + it * 16;
        ushort4 o;
        o.x = f2bf(tile[cc + 0][n]); o.y = f2bf(tile[cc + 1][n]);
        o.z = f2bf(tile[cc + 2][n]); o.w = f2bf(tile[cc + 3][n]);
        *reinterpret_cast<ushort4*>(dst + (size_t)(n0 + n) * EMB + k0 + cc) = o;
    }
}

// ---------------------------------------------------------------------------
// MFMA projection GEMM. 128x64 tile, 4 waves 2x2.
// z==2 (V) writes TRANSPOSED per-head: vbT[(b*NHEAD+h)*DPH + d][s] (bf16).
// ---------------------------------------------------------------------------
__global__ __launch_bounds__(256) void gemm_proj_mfma(
    const float* __restrict__ Aq, const float* __restrict__ Ak, const float* __restrict__ Av,
    const unsigned short* __restrict__ Wt,
    const float* __restrict__ bqp, const float* __restrict__ bkp, const float* __restrict__ bvp,
    unsigned short* __restrict__ oq, unsigned short* __restrict__ okp, unsigned short* __restrict__ ov)
{
    const int z = blockIdx.z;
    const float* A = (z == 0) ? Aq : (z == 1) ? Ak : Av;
    const unsigned short* W = Wt + (size_t)z * EMB * EMB;
    const float* bias = (z == 0) ? bqp : (z == 1) ? bkp : bvp;
    unsigned short* out = (z == 0) ? oq : (z == 1) ? okp : ov;

    const int n0 = blockIdx.x * 64;
    const int m0 = blockIdx.y * 128;
    const int tid = threadIdx.x;
    const int lane = tid & 63;
    const int wid = tid >> 6;
    const int wr = wid >> 1, wc = wid & 1;

    __shared__ __align__(16) unsigned char smA[128 * 64 * 2];
    __shared__ __align__(16) unsigned char smB[64 * 64 * 2];

    f32x4 acc[4][2] = {};

    for (int k0 = 0; k0 < EMB; k0 += 64) {
        __syncthreads();
        #pragma unroll
        for (int it = 0; it < 4; ++it) {
            int w = it * 256 + tid;
            int row = w >> 3, kc = w & 7;
            const float* src = A + (size_t)(m0 + row) * EMB + k0 + kc * 8;
            float4 v0 = *reinterpret_cast<const float4*>(src);
            float4 v1 = *reinterpret_cast<const float4*>(src + 4);
            union { unsigned short s[8]; uint4 u; } p;
            p.s[0] = f2bf(v0.x); p.s[1] = f2bf(v0.y); p.s[2] = f2bf(v0.z); p.s[3] = f2bf(v0.w);
            p.s[4] = f2bf(v1.x); p.s[5] = f2bf(v1.y); p.s[6] = f2bf(v1.z); p.s[7] = f2bf(v1.w);
            unsigned byte = ((unsigned)row << 7) + ((unsigned)kc << 4);
            byte ^= (unsigned)((row & 7) << 4);
            *reinterpret_cast<uint4*>(smA + byte) = p.u;
        }
        #pragma unroll
        for (int it = 0; it < 2; ++it) {
            int w = it * 256 + tid;
            int row = w >> 3, kc = w & 7;
            uint4 raw = *reinterpret_cast<const uint4*>(W + (size_t)(n0 + row) * EMB + k0 + kc * 8);
            unsigned byte = ((unsigned)row << 7) + ((unsigned)kc << 4);
            byte ^= (unsigned)((row & 7) << 4);
            *reinterpret_cast<uint4*>(smB + byte) = raw;
        }
        __syncthreads();

        #pragma unroll
        for (int ks = 0; ks < 2; ++ks) {
            bf16x8 bfrag[2];
            #pragma unroll
            for (int ni = 0; ni < 2; ++ni) {
                int col = wc * 32 + ni * 16 + (lane & 15);
                unsigned byte = ((unsigned)col << 7) + (unsigned)(ks << 6) + (unsigned)((lane >> 4) << 4);
                byte ^= (unsigned)((col & 7) << 4);
                bfrag[ni] = *reinterpret_cast<const bf16x8*>(smB + byte);
            }
            #pragma unroll
            for (int mi = 0; mi < 4; ++mi) {
                int row = wr * 64 + mi * 16 + (lane & 15);
                unsigned byte = ((unsigned)row << 7) + (unsigned)(ks << 6) + (unsigned)((lane >> 4) << 4);
                byte ^= (unsigned)((row & 7) << 4);
                bf16x8 afrag = *reinterpret_cast<const bf16x8*>(smA + byte);
                #pragma unroll
                for (int ni = 0; ni < 2; ++ni)
                    acc[mi][ni] = __builtin_amdgcn_mfma_f32_16x16x32_bf16(afrag, bfrag[ni], acc[mi][ni], 0, 0, 0);
            }
        }
    }

    if (z == 2) {
        #pragma unroll
        for (int ni = 0; ni < 2; ++ni) {
            int colg = n0 + wc * 32 + ni * 16 + (lane & 15);
            float bj = bias[colg];
            int hh = colg >> 6, dd = colg & 63;
            #pragma unroll
            for (int mi = 0; mi < 4; ++mi) {
                int rbase = m0 + wr * 64 + mi * 16 + ((lane >> 4) << 2);
                int bb = rbase >> 9, ss = rbase & 511;
                ushort4 o;
                o.x = f2bf(acc[mi][ni][0] + bj);
                o.y = f2bf(acc[mi][ni][1] + bj);
                o.z = f2bf(acc[mi][ni][2] + bj);
                o.w = f2bf(acc[mi][ni][3] + bj);
                *reinterpret_cast<ushort4*>(out + ((size_t)(bb * NHEAD + hh) * DPH + dd) * S_LEN + ss) = o;
            }
        }
    } else {
        #pragma unroll
        for (int ni = 0; ni < 2; ++ni) {
            int colg = n0 + wc * 32 + ni * 16 + (lane & 15);
            float bj = bias[colg];
            #pragma unroll
            for (int mi = 0; mi < 4; ++mi) {
                int rbase = m0 + wr * 64 + mi * 16 + ((lane >> 4) << 2);
                #pragma unroll
                for (int q = 0; q < 4; ++q)
                    out[(size_t)(rbase + q) * EMB + colg] = f2bf(acc[mi][ni][q] + bj);
            }
        }
    }
}

// ---------------------------------------------------------------------------
// MFMA output GEMM (validated round 5).
// ---------------------------------------------------------------------------
__global__ __launch_bounds__(256) void gemm_out_mfma(
    const unsigned short* __restrict__ A,
    const unsigned short* __restrict__ W,
    const float* __restrict__ bias,
    float* __restrict__ out)
{
    const int n0 = blockIdx.x * 64;
    const int m0 = blockIdx.y * 128;
    const int tid = threadIdx.x;
    const int lane = tid & 63;
    const int wid = tid >> 6;
    const int wr = wid >> 1, wc = wid & 1;

    __shared__ __align__(16) unsigned char smA[128 * 64 * 2];
    __shared__ __align__(16) unsigned char smB[64 * 64 * 2];

    f32x4 acc[4][2] = {};

    for (int k0 = 0; k0 < EMB; k0 += 64) {
        __syncthreads();
        #pragma unroll
        for (int it = 0; it < 4; ++it) {
            int w = it * 256 + tid;
            int row = w >> 3, kc = w & 7;
            uint4 raw = *reinterpret_cast<const uint4*>(A + (size_t)(m0 + row) * EMB + k0 + kc * 8);
            unsigned byte = ((unsigned)row << 7) + ((unsigned)kc << 4);
            byte ^= (unsigned)((row & 7) << 4);
            *reinterpret_cast<uint4*>(smA + byte) = raw;
        }
        #pragma unroll
        for (int it = 0; it < 2; ++it) {
            int w = it * 256 + tid;
            int row = w >> 3, kc = w & 7;
            uint4 raw = *reinterpret_cast<const uint4*>(W + (size_t)(n0 + row) * EMB + k0 + kc * 8);
            unsigned byte = ((unsigned)row << 7) + ((unsigned)kc << 4);
            byte ^= (unsigned)((row & 7) << 4);
            *reinterpret_cast<uint4*>(smB + byte) = raw;
        }
        __syncthreads();

        #pragma unroll
        for (int ks = 0; ks < 2; ++ks) {
            bf16x8 bfrag[2];
            #pragma unroll
            for (int ni = 0; ni < 2; ++ni) {
                int col = wc * 32 + ni * 16 + (lane & 15);
                unsigned byte = ((unsigned)col << 7) + (unsigned)(ks << 6) + (unsigned)((lane >> 4) << 4);
                byte ^= (unsigned)((col & 7) << 4);
                bfrag[ni] = *reinterpret_cast<const bf16x8*>(smB + byte);
            }
            #pragma unroll
            for (int mi = 0; mi < 4; ++mi) {
                int row = wr * 64 + mi * 16 + (lane & 15);
                unsigned byte = ((unsigned)row << 7) + (unsigned)(ks << 6) + (unsigned)((lane >> 4) << 4);
                byte ^= (unsigned)((row & 7) << 4);
                bf16x8 afrag = *reinterpret_cast<const bf16x8*>(smA + byte);
                #pragma unroll
                for (int ni = 0; ni < 2; ++ni)
                    acc[mi][ni] = __builtin_amdgcn_mfma_f32_16x16x32_bf16(afrag, bfrag[ni], acc[mi][ni], 0, 0, 0);
            }
        }
    }

    #pragma unroll
    for (int ni = 0; ni < 2; ++ni) {
        int colg = n0 + wc * 32 + ni * 16 + (lane & 15);
        float bj = bias[colg];
        #pragma unroll
        for (int mi = 0; mi < 4; ++mi) {
            int rbase = m0 + wr * 64 + mi * 16 + ((lane >> 4) << 2);
            #pragma unroll
            for (int q = 0; q < 4; ++q)
                out[(size_t)(rbase + q) * EMB + colg] = acc[mi][ni][q] + bj;
        }
    }
}

// ---------------------------------------------------------------------------
// Relation-aware flash attention, v8 = v4 structure + VALU diet:
//  - no-max softmax (v7-validated): p = exp2(fma(qk, C, qa')), C=0.125*log2e,
//    qa'_r = qrel_r*C - 11.5416; no per-tile max/rescale/shuffles
//  - no rel clamp (rel in {0,1,2} by construction)
//  - 2 masked es accumulators; es0 = l - es1 - es2
//  - l/es cross-lane reduce ONCE at the end
// Block = 512 thr = 8 waves (4 qstrips x 2 tgroups), tgroup = 4 tiles of 64 t.
// Loads issued before loop-top barrier (v4's latency hiding). 2-group merge.
// ---------------------------------------------------------------------------
__global__ __launch_bounds__(512) void attn_mfma(
    const unsigned short* __restrict__ qb,
    const unsigned short* __restrict__ kb,
    const unsigned short* __restrict__ vbT,
    const int* __restrict__ rel,
    const float* __restrict__ rel_k, const float* __restrict__ rel_v,
    unsigned short* __restrict__ ob)
{
    const int s0 = blockIdx.x * 64;
    const int h  = blockIdx.y;
    const int b  = blockIdx.z;
    const int tid = threadIdx.x;
    const int lane = tid & 63;
    const int wid = tid >> 6;          // 0..7
    const int qstrip = wid & 3;        // 16-row strip
    const int tgroup = wid >> 2;       // t-half
    const int sl = lane & 15;
    const int tg = lane >> 4;

    __shared__ __align__(16) unsigned char smQ[64 * 128];
    __shared__ __align__(16) unsigned char smK[2 * 64 * 128];   // per t-group; accL after loop
    __shared__ __align__(16) unsigned char smVt[2 * 64 * 128];  // per t-group; stats after loop
    __shared__ __align__(16) unsigned char smP[8 * 16 * 128];   // per wave
    __shared__ float qrel_s[64][4];
    __shared__ float relv_s[NREL][64];

    const unsigned short* qsrc  = qb + ((size_t)(b * S_LEN + s0)) * EMB + h * DPH;
    const unsigned short* ksrc  = kb + ((size_t)b * S_LEN) * EMB + h * DPH;
    const unsigned short* vsrcT = vbT + (size_t)(b * NHEAD + h) * DPH * S_LEN;

    // --- stage Q (64x64 bf16, swizzled): 512 thr x 1 uint4 ---
    {
        int row = tid >> 3, kc = tid & 7;
        uint4 raw = *reinterpret_cast<const uint4*>(qsrc + (size_t)row * EMB + kc * 8);
        unsigned byte = ((unsigned)row << 7) + ((unsigned)kc << 4);
        byte ^= (unsigned)((row & 7) << 4);
        *reinterpret_cast<uint4*>(smQ + byte) = raw;
    }
    if (tid < NREL * 64) {
        int rr = tid >> 6, d = tid & 63;
        relv_s[rr][d] = rel_v[rr * DPH + d];
    }
    __syncthreads();
    if (tid < 192) {
        int r = tid / 3, rr = tid - 3 * (tid / 3);
        float s = 0.f;
        #pragma unroll
        for (int dc = 0; dc < 32; ++dc) {
            unsigned byte = ((unsigned)r << 7) + (unsigned)(dc << 2);
            byte ^= (unsigned)((r & 7) << 4);
            unsigned u = *reinterpret_cast<const unsigned*>(smQ + byte);
            s += bf2f((unsigned short)(u & 0xffff)) * rel_k[rr * DPH + dc * 2]
               + bf2f((unsigned short)(u >> 16))   * rel_k[rr * DPH + dc * 2 + 1];
        }
        qrel_s[r][rr] = s;
    }
    __syncthreads();

    const int srow = qstrip * 16 + sl;
    // fold scale, log2e and the fixed shift into the per-row rel biases:
    // p = exp2(qk*CEXP + qa'),  qa'_r = qrel_r*CEXP - SHIFT
    const float CEXP  = 0.125f * 1.4426950408889634f;
    const float SHIFT = 11.541560327111707f;           // 8 * log2(e)
    const float qa0 = qrel_s[srow][0] * CEXP - SHIFT;
    const float qa1 = qrel_s[srow][1] * CEXP - SHIFT;
    const float qa2 = qrel_s[srow][2] * CEXP - SHIFT;

    bf16x8 qfrag[2];
    #pragma unroll
    for (int ks = 0; ks < 2; ++ks) {
        unsigned byte = ((unsigned)srow << 7) + (unsigned)(ks << 6) + (unsigned)(tg << 4);
        byte ^= (unsigned)((srow & 7) << 4);
        qfrag[ks] = *reinterpret_cast<const bf16x8*>(smQ + byte);
    }

    const int* rrow_s = rel + ((size_t)(b * S_LEN + s0 + srow)) * S_LEN;
    const unsigned pbase = (unsigned)(wid * 2048);

    const int gtid  = tid & 255;      // thread id within t-group (4 waves)
    const int ldrow = gtid >> 3;      // 0..31
    const int ldkc  = gtid & 7;       // 0..7
    const unsigned wbyte0 = (((unsigned)ldrow << 7) + ((unsigned)ldkc << 4))
                            ^ ((unsigned)((ldrow & 7) << 4));
    const unsigned wbyte1 = wbyte0 + 4096;   // row+32: same swizzle bits
    unsigned char* kbase = smK  + tgroup * 8192;
    unsigned char* vbase = smVt + tgroup * 8192;

    float l_run = 0.f, es1 = 0.f, es2 = 0.f;
    f32x4 acc_pv[4] = {};

    #pragma unroll
    for (int i = 0; i < 4; ++i) {
        const int t0 = (tgroup * 4 + i) * 64;

        // issue this tile's global loads BEFORE the barrier (latency overlap)
        uint4 k0 = *reinterpret_cast<const uint4*>(ksrc + (size_t)(t0 + ldrow) * EMB + ldkc * 8);
        uint4 k1 = *reinterpret_cast<const uint4*>(ksrc + (size_t)(t0 + ldrow + 32) * EMB + ldkc * 8);
        uint4 v0 = *reinterpret_cast<const uint4*>(vsrcT + (size_t)ldrow * S_LEN + t0 + ldkc * 8);
        uint4 v1 = *reinterpret_cast<const uint4*>(vsrcT + (size_t)(ldrow + 32) * S_LEN + t0 + ldkc * 8);
        int4 rr[4];
        #pragma unroll
        for (int t4 = 0; t4 < 4; ++t4)
            rr[t4] = *reinterpret_cast<const int4*>(rrow_s + t0 + t4 * 16 + tg * 4);

        __syncthreads();   // prior compute's LDS reads done
        *reinterpret_cast<uint4*>(kbase + wbyte0) = k0;
        *reinterpret_cast<uint4*>(kbase + wbyte1) = k1;
        *reinterpret_cast<uint4*>(vbase + wbyte0) = v0;
        *reinterpret_cast<uint4*>(vbase + wbyte1) = v1;
        __syncthreads();

        // ---- QK^T: C[t][s] ----
        f32x4 sacc[4] = {};
        #pragma unroll
        for (int ks = 0; ks < 2; ++ks)
            #pragma unroll
            for (int t4 = 0; t4 < 4; ++t4) {
                int trow = t4 * 16 + sl;
                unsigned byte = ((unsigned)trow << 7) + (unsigned)(ks << 6) + (unsigned)(tg << 4);
                byte ^= (unsigned)((trow & 7) << 4);
                bf16x8 kf = *reinterpret_cast<const bf16x8*>(kbase + byte);
                sacc[t4] = __builtin_amdgcn_mfma_f32_16x16x32_bf16(kf, qfrag[ks], sacc[t4], 0, 0, 0);
            }

        // ---- no-max softmax + masked es, minimal VALU ----
        #pragma unroll
        for (int t4 = 0; t4 < 4; ++t4) {
            int rv[4] = {rr[t4].x, rr[t4].y, rr[t4].z, rr[t4].w};
            #pragma unroll
            for (int j = 0; j < 4; ++j) {
                int r = rv[j];
                float qa = (r == 0) ? qa0 : ((r == 1) ? qa1 : qa2);
                float p = __builtin_amdgcn_exp2f(fmaf(sacc[t4][j], CEXP, qa));
                sacc[t4][j] = p;
                l_run += p;
                es1 += (r == 1) ? p : 0.f;
                es2 += (r == 2) ? p : 0.f;
            }
        }

        // P -> LDS bf16 (per-wave region; same-wave write->read)
        #pragma unroll
        for (int t4 = 0; t4 < 4; ++t4)
            #pragma unroll
            for (int pr = 0; pr < 2; ++pr) {
                unsigned u = (unsigned)f2bf(sacc[t4][2 * pr]) |
                             ((unsigned)f2bf(sacc[t4][2 * pr + 1]) << 16);
                unsigned byte = pbase + ((unsigned)sl << 7) + (unsigned)(t4 * 32 + tg * 8 + pr * 4);
                byte ^= (unsigned)((sl & 7) << 4);
                *reinterpret_cast<unsigned*>(smP + byte) = u;
            }

        // PV: acc[s][d] += P[s][t] V[t][d]
        #pragma unroll
        for (int ks = 0; ks < 2; ++ks) {
            unsigned pbyte = pbase + ((unsigned)sl << 7) + (unsigned)(ks << 6) + (unsigned)(tg << 4);
            pbyte ^= (unsigned)((sl & 7) << 4);
            bf16x8 pf = *reinterpret_cast<const bf16x8*>(smP + pbyte);
            #pragma unroll
            for (int dt = 0; dt < 4; ++dt) {
                int d = dt * 16 + sl;
                unsigned vbyte = ((unsigned)d << 7) + (unsigned)(ks << 6) + (unsigned)(tg << 4);
                vbyte ^= (unsigned)((d & 7) << 4);
                bf16x8 vf = *reinterpret_cast<const bf16x8*>(vbase + vbyte);
                acc_pv[dt] = __builtin_amdgcn_mfma_f32_16x16x32_bf16(pf, vf, acc_pv[dt], 0, 0, 0);
            }
        }
    }

    // end-only cross-lane reduce: full row sums over this group's 256 t
    l_run += __shfl_xor(l_run, 16);  l_run += __shfl_xor(l_run, 32);
    es1   += __shfl_xor(es1, 16);    es1   += __shfl_xor(es1, 32);
    es2   += __shfl_xor(es2, 16);    es2   += __shfl_xor(es2, 32);

    // ---- publish partials & merge the two t-groups (weights all 1) ----
    __syncthreads();   // K/V LDS no longer needed; safe to reuse
    float* accL  = reinterpret_cast<float*>(smK);    // [64 rows][64 d]
    float* stats = reinterpret_cast<float*>(smVt);   // l[2][64], es1[2][64], es2[2][64]

    if (tg == 0) {
        stats[tgroup * 64 + srow]        = l_run;
        stats[128 + tgroup * 64 + srow]  = es1;
        stats[256 + tgroup * 64 + srow]  = es2;
    }
    if (tgroup == 1) {
        #pragma unroll
        for (int dt = 0; dt < 4; ++dt)
            #pragma unroll
            for (int r = 0; r < 4; ++r)
                accL[(qstrip * 16 + tg * 4 + r) * 64 + dt * 16 + sl] = acc_pv[dt][r];
    }
    __syncthreads();

    if (tgroup == 0) {
        unsigned short* dst = ob + ((size_t)(b * S_LEN + s0 + qstrip * 16)) * EMB + h * DPH;
        #pragma unroll
        for (int r = 0; r < 4; ++r) {
            const int row64 = qstrip * 16 + tg * 4 + r;
            float lt  = stats[row64]       + stats[64 + row64];
            float e1t = stats[128 + row64] + stats[192 + row64];
            float e2t = stats[256 + row64] + stats[320 + row64];
            float e0t = lt - e1t - e2t;
            float linv = 1.f / lt;
            #pragma unroll
            for (int dt = 0; dt < 4; ++dt) {
                int d = dt * 16 + sl;
                float o = acc_pv[dt][r] + accL[row64 * 64 + d];
                o += e0t * relv_s[0][d] + e1t * relv_s[1][d] + e2t * relv_s[2][d];
                o *= linv;
                dst[(size_t)(tg * 4 + r) * EMB + d] = f2bf(o);
            }
        }
    }
}

extern "C" void kernel_launch(void* const* d_in, const int* in_sizes, int n_in,
                              void* d_out, int out_size, void* d_ws, size_t ws_size,
                              hipStream_t stream) {
    int iq=0, ik=1, iv=2, irel=3, iWq=4, ibq=5, iWk=6, ibk=7, iWv=8, ibv=9, iWo=10, ibo=11, irk=12, irv=13;
    if (n_in >= 14 && in_sizes[0] == 512 * 512) {
        iWk=0; iWo=1; iWq=2; iWv=3; ibk=4; ibo=5; ibq=6; ibv=7;
        irel=8; ik=9; iq=10; irk=11; irv=12; iv=13;
    }

    const float* q_in = (const float*)d_in[iq];
    const float* k_in = (const float*)d_in[ik];
    const float* v_in = (const float*)d_in[iv];
    const int*   grel = (const int*)d_in[irel];
    const float* Wq = (const float*)d_in[iWq];
    const float* bq = (const float*)d_in[ibq];
    const float* Wk = (const float*)d_in[iWk];
    const float* bk = (const float*)d_in[ibk];
    const float* Wv = (const float*)d_in[iWv];
    const float* bv = (const float*)d_in[ibv];
    const float* Wo = (const float*)d_in[iWo];
    const float* bo = (const float*)d_in[ibo];
    const float* rk = (const float*)d_in[irk];
    const float* rv = (const float*)d_in[irv];

    unsigned short* qb  = (unsigned short*)d_ws;
    unsigned short* kb  = qb + (size_t)4096 * 512;
    unsigned short* vbT = kb + (size_t)4096 * 512;   // [b*NHEAD+h][d][s]
    unsigned short* ab  = vbT + (size_t)4096 * 512;
    unsigned short* wt  = ab + (size_t)4096 * 512;

    dim3 blk(256);
    transpose_w<<<dim3(8, 8, 4), blk, 0, stream>>>(Wq, Wk, Wv, Wo, wt);
    gemm_proj_mfma<<<dim3(8, 32, 3), blk, 0, stream>>>(q_in, k_in, v_in, wt, bq, bk, bv, qb, kb, vbT);
    attn_mfma<<<dim3(8, NHEAD, BATCH), dim3(512), 0, stream>>>(qb, kb, vbT, grel, rk, rv, ab);
    gemm_out_mfma<<<dim3(8, 32), blk, 0, stream>>>(ab, wt + (size_t)3 * 512 * 512, bo, (float*)d_out);
}

// Round 16
// 62.946 us; speedup vs baseline: 1.5092x; 1.1181x over previous
//
#include <hip/hip_runtime.h>
#include <hip/hip_bf16.h>

#define S_LEN 512
#define EMB   512
#define NHEAD 8
#define DPH   64
#define NREL  3
#define BATCH 8

typedef __attribute__((ext_vector_type(8))) short bf16x8;
typedef __attribute__((ext_vector_type(4))) float f32x4;

__device__ __forceinline__ float bf2f(unsigned short u) {
    union { unsigned int i; float f; } cv;
    cv.i = ((unsigned int)u) << 16;
    return cv.f;
}
__device__ __forceinline__ unsigned short f2bf(float f) {
    __hip_bfloat16 h = __float2bfloat16(f);
    return *reinterpret_cast<unsigned short*>(&h);
}

// ---------------------------------------------------------------------------
// Weight transpose: Wt[z][n][k] (bf16) = W[z][k][n] (f32), z in {q,k,v,o}.
// ---------------------------------------------------------------------------
__global__ __launch_bounds__(256) void transpose_w(
    const float* __restrict__ Wq, const float* __restrict__ Wk,
    const float* __restrict__ Wv, const float* __restrict__ Wo,
    unsigned short* __restrict__ Wt)
{
    const int z = blockIdx.z;
    const float* W = (z == 0) ? Wq : (z == 1) ? Wk : (z == 2) ? Wv : Wo;
    unsigned short* dst = Wt + (size_t)z * EMB * EMB;

    __shared__ float tile[64][65];
    const int n0 = blockIdx.x * 64, k0 = blockIdx.y * 64;
    const int t = threadIdx.x;
    const int cr = t >> 4, cc = (t & 15) * 4;

    #pragma unroll
    for (int it = 0; it < 4; ++it) {
        int r = cr + it * 16;
        float4 v = *reinterpret_cast<const float4*>(W + (size_t)(k0 + r) * EMB + n0 + cc);
        tile[r][cc + 0] = v.x; tile[r][cc + 1] = v.y;
        tile[r][cc + 2] = v.z; tile[r][cc + 3] = v.w;
    }
    __syncthreads();
    #pragma unroll
    for (int it = 0; it < 4; ++it) {
        int n = cr + it * 16;
        ushort4 o;
        o.x = f2bf(tile[cc + 0][n]); o.y = f2bf(tile[cc + 1][n]);
        o.z = f2bf(tile[cc + 2][n]); o.w = f2bf(tile[cc + 3][n]);
        *reinterpret_cast<ushort4*>(dst + (size_t)(n0 + n) * EMB + k0 + cc) = o;
    }
}

// ---------------------------------------------------------------------------
// MFMA projection GEMM, 128x128 tile, BK=64, 4 waves 2x2 (wave = 64x64).
// z==2 (V) writes TRANSPOSED per-head: vbT[(b*NHEAD+h)*DPH + d][s] (bf16).
// grid (4, 32, 3).
// ---------------------------------------------------------------------------
__global__ __launch_bounds__(256) void gemm_proj_mfma(
    const float* __restrict__ Aq, const float* __restrict__ Ak, const float* __restrict__ Av,
    const unsigned short* __restrict__ Wt,
    const float* __restrict__ bqp, const float* __restrict__ bkp, const float* __restrict__ bvp,
    unsigned short* __restrict__ oq, unsigned short* __restrict__ okp, unsigned short* __restrict__ ov)
{
    const int z = blockIdx.z;
    const float* A = (z == 0) ? Aq : (z == 1) ? Ak : Av;
    const unsigned short* W = Wt + (size_t)z * EMB * EMB;
    const float* bias = (z == 0) ? bqp : (z == 1) ? bkp : bvp;
    unsigned short* out = (z == 0) ? oq : (z == 1) ? okp : ov;

    const int n0 = blockIdx.x * 128;
    const int m0 = blockIdx.y * 128;
    const int tid = threadIdx.x;
    const int lane = tid & 63;
    const int wid = tid >> 6;
    const int wr = wid >> 1, wc = wid & 1;

    __shared__ __align__(16) unsigned char smA[128 * 64 * 2];
    __shared__ __align__(16) unsigned char smB[128 * 64 * 2];

    f32x4 acc[4][4] = {};

    for (int k0 = 0; k0 < EMB; k0 += 64) {
        __syncthreads();
        #pragma unroll
        for (int it = 0; it < 4; ++it) {
            int w = it * 256 + tid;
            int row = w >> 3, kc = w & 7;
            const float* src = A + (size_t)(m0 + row) * EMB + k0 + kc * 8;
            float4 v0 = *reinterpret_cast<const float4*>(src);
            float4 v1 = *reinterpret_cast<const float4*>(src + 4);
            union { unsigned short s[8]; uint4 u; } p;
            p.s[0] = f2bf(v0.x); p.s[1] = f2bf(v0.y); p.s[2] = f2bf(v0.z); p.s[3] = f2bf(v0.w);
            p.s[4] = f2bf(v1.x); p.s[5] = f2bf(v1.y); p.s[6] = f2bf(v1.z); p.s[7] = f2bf(v1.w);
            unsigned byte = ((unsigned)row << 7) + ((unsigned)kc << 4);
            byte ^= (unsigned)((row & 7) << 4);
            *reinterpret_cast<uint4*>(smA + byte) = p.u;
        }
        #pragma unroll
        for (int it = 0; it < 4; ++it) {
            int w = it * 256 + tid;
            int row = w >> 3, kc = w & 7;
            uint4 raw = *reinterpret_cast<const uint4*>(W + (size_t)(n0 + row) * EMB + k0 + kc * 8);
            unsigned byte = ((unsigned)row << 7) + ((unsigned)kc << 4);
            byte ^= (unsigned)((row & 7) << 4);
            *reinterpret_cast<uint4*>(smB + byte) = raw;
        }
        __syncthreads();

        #pragma unroll
        for (int ks = 0; ks < 2; ++ks) {
            bf16x8 bfrag[4];
            #pragma unroll
            for (int ni = 0; ni < 4; ++ni) {
                int col = wc * 64 + ni * 16 + (lane & 15);
                unsigned byte = ((unsigned)col << 7) + (unsigned)(ks << 6) + (unsigned)((lane >> 4) << 4);
                byte ^= (unsigned)((col & 7) << 4);
                bfrag[ni] = *reinterpret_cast<const bf16x8*>(smB + byte);
            }
            #pragma unroll
            for (int mi = 0; mi < 4; ++mi) {
                int row = wr * 64 + mi * 16 + (lane & 15);
                unsigned byte = ((unsigned)row << 7) + (unsigned)(ks << 6) + (unsigned)((lane >> 4) << 4);
                byte ^= (unsigned)((row & 7) << 4);
                bf16x8 afrag = *reinterpret_cast<const bf16x8*>(smA + byte);
                #pragma unroll
                for (int ni = 0; ni < 4; ++ni)
                    acc[mi][ni] = __builtin_amdgcn_mfma_f32_16x16x32_bf16(afrag, bfrag[ni], acc[mi][ni], 0, 0, 0);
            }
        }
    }

    if (z == 2) {
        #pragma unroll
        for (int ni = 0; ni < 4; ++ni) {
            int colg = n0 + wc * 64 + ni * 16 + (lane & 15);
            float bj = bias[colg];
            int hh = colg >> 6, dd = colg & 63;
            #pragma unroll
            for (int mi = 0; mi < 4; ++mi) {
                int rbase = m0 + wr * 64 + mi * 16 + ((lane >> 4) << 2);
                int bb = rbase >> 9, ss = rbase & 511;
                ushort4 o;
                o.x = f2bf(acc[mi][ni][0] + bj);
                o.y = f2bf(acc[mi][ni][1] + bj);
                o.z = f2bf(acc[mi][ni][2] + bj);
                o.w = f2bf(acc[mi][ni][3] + bj);
                *reinterpret_cast<ushort4*>(out + ((size_t)(bb * NHEAD + hh) * DPH + dd) * S_LEN + ss) = o;
            }
        }
    } else {
        #pragma unroll
        for (int ni = 0; ni < 4; ++ni) {
            int colg = n0 + wc * 64 + ni * 16 + (lane & 15);
            float bj = bias[colg];
            #pragma unroll
            for (int mi = 0; mi < 4; ++mi) {
                int rbase = m0 + wr * 64 + mi * 16 + ((lane >> 4) << 2);
                #pragma unroll
                for (int q = 0; q < 4; ++q)
                    out[(size_t)(rbase + q) * EMB + colg] = f2bf(acc[mi][ni][q] + bj);
            }
        }
    }
}

// ---------------------------------------------------------------------------
// MFMA output GEMM, 128x128 tile. A = bf16 ws, out = f32 d_out. grid (4, 32).
// ---------------------------------------------------------------------------
__global__ __launch_bounds__(256) void gemm_out_mfma(
    const unsigned short* __restrict__ A,
    const unsigned short* __restrict__ W,
    const float* __restrict__ bias,
    float* __restrict__ out)
{
    const int n0 = blockIdx.x * 128;
    const int m0 = blockIdx.y * 128;
    const int tid = threadIdx.x;
    const int lane = tid & 63;
    const int wid = tid >> 6;
    const int wr = wid >> 1, wc = wid & 1;

    __shared__ __align__(16) unsigned char smA[128 * 64 * 2];
    __shared__ __align__(16) unsigned char smB[128 * 64 * 2];

    f32x4 acc[4][4] = {};

    for (int k0 = 0; k0 < EMB; k0 += 64) {
        __syncthreads();
        #pragma unroll
        for (int it = 0; it < 4; ++it) {
            int w = it * 256 + tid;
            int row = w >> 3, kc = w & 7;
            uint4 raw = *reinterpret_cast<const uint4*>(A + (size_t)(m0 + row) * EMB + k0 + kc * 8);
            unsigned byte = ((unsigned)row << 7) + ((unsigned)kc << 4);
            byte ^= (unsigned)((row & 7) << 4);
            *reinterpret_cast<uint4*>(smA + byte) = raw;
        }
        #pragma unroll
        for (int it = 0; it < 4; ++it) {
            int w = it * 256 + tid;
            int row = w >> 3, kc = w & 7;
            uint4 raw = *reinterpret_cast<const uint4*>(W + (size_t)(n0 + row) * EMB + k0 + kc * 8);
            unsigned byte = ((unsigned)row << 7) + ((unsigned)kc << 4);
            byte ^= (unsigned)((row & 7) << 4);
            *reinterpret_cast<uint4*>(smB + byte) = raw;
        }
        __syncthreads();

        #pragma unroll
        for (int ks = 0; ks < 2; ++ks) {
            bf16x8 bfrag[4];
            #pragma unroll
            for (int ni = 0; ni < 4; ++ni) {
                int col = wc * 64 + ni * 16 + (lane & 15);
                unsigned byte = ((unsigned)col << 7) + (unsigned)(ks << 6) + (unsigned)((lane >> 4) << 4);
                byte ^= (unsigned)((col & 7) << 4);
                bfrag[ni] = *reinterpret_cast<const bf16x8*>(smB + byte);
            }
            #pragma unroll
            for (int mi = 0; mi < 4; ++mi) {
                int row = wr * 64 + mi * 16 + (lane & 15);
                unsigned byte = ((unsigned)row << 7) + (unsigned)(ks << 6) + (unsigned)((lane >> 4) << 4);
                byte ^= (unsigned)((row & 7) << 4);
                bf16x8 afrag = *reinterpret_cast<const bf16x8*>(smA + byte);
                #pragma unroll
                for (int ni = 0; ni < 4; ++ni)
                    acc[mi][ni] = __builtin_amdgcn_mfma_f32_16x16x32_bf16(afrag, bfrag[ni], acc[mi][ni], 0, 0, 0);
            }
        }
    }

    #pragma unroll
    for (int ni = 0; ni < 4; ++ni) {
        int colg = n0 + wc * 64 + ni * 16 + (lane & 15);
        float bj = bias[colg];
        #pragma unroll
        for (int mi = 0; mi < 4; ++mi) {
            int rbase = m0 + wr * 64 + mi * 16 + ((lane >> 4) << 2);
            #pragma unroll
            for (int q = 0; q < 4; ++q)
                out[(size_t)(rbase + q) * EMB + colg] = acc[mi][ni][q] + bj;
        }
    }
}

// ---------------------------------------------------------------------------
// Relation-aware flash attention, v9 = v8 + P/Q LDS alias (waves 0-3's P
// regions reuse smQ, which is dead after the prologue fragment loads; all
// qfrag/qrel reads complete before any wave can pass the loop's first
// barriers, which precede the first P write). LDS 59.4 -> 51.2 KB
// -> 3 blocks/CU.
// ---------------------------------------------------------------------------
__global__ __launch_bounds__(512) void attn_mfma(
    const unsigned short* __restrict__ qb,
    const unsigned short* __restrict__ kb,
    const unsigned short* __restrict__ vbT,
    const int* __restrict__ rel,
    const float* __restrict__ rel_k, const float* __restrict__ rel_v,
    unsigned short* __restrict__ ob)
{
    const int s0 = blockIdx.x * 64;
    const int h  = blockIdx.y;
    const int b  = blockIdx.z;
    const int tid = threadIdx.x;
    const int lane = tid & 63;
    const int wid = tid >> 6;          // 0..7
    const int qstrip = wid & 3;        // 16-row strip
    const int tgroup = wid >> 2;       // t-half
    const int sl = lane & 15;
    const int tg = lane >> 4;

    __shared__ __align__(16) unsigned char smQ[64 * 128];       // Q; P for waves 0-3 after prologue
    __shared__ __align__(16) unsigned char smK[2 * 64 * 128];   // per t-group; accL after loop
    __shared__ __align__(16) unsigned char smVt[2 * 64 * 128];  // per t-group; stats after loop
    __shared__ __align__(16) unsigned char smP2[4 * 16 * 128];  // P for waves 4-7
    __shared__ float qrel_s[64][4];
    __shared__ float relv_s[NREL][64];

    const unsigned short* qsrc  = qb + ((size_t)(b * S_LEN + s0)) * EMB + h * DPH;
    const unsigned short* ksrc  = kb + ((size_t)b * S_LEN) * EMB + h * DPH;
    const unsigned short* vsrcT = vbT + (size_t)(b * NHEAD + h) * DPH * S_LEN;

    // --- stage Q (64x64 bf16, swizzled): 512 thr x 1 uint4 ---
    {
        int row = tid >> 3, kc = tid & 7;
        uint4 raw = *reinterpret_cast<const uint4*>(qsrc + (size_t)row * EMB + kc * 8);
        unsigned byte = ((unsigned)row << 7) + ((unsigned)kc << 4);
        byte ^= (unsigned)((row & 7) << 4);
        *reinterpret_cast<uint4*>(smQ + byte) = raw;
    }
    if (tid < NREL * 64) {
        int rr = tid >> 6, d = tid & 63;
        relv_s[rr][d] = rel_v[rr * DPH + d];
    }
    __syncthreads();
    if (tid < 192) {
        int r = tid / 3, rr = tid - 3 * (tid / 3);
        float s = 0.f;
        #pragma unroll
        for (int dc = 0; dc < 32; ++dc) {
            unsigned byte = ((unsigned)r << 7) + (unsigned)(dc << 2);
            byte ^= (unsigned)((r & 7) << 4);
            unsigned u = *reinterpret_cast<const unsigned*>(smQ + byte);
            s += bf2f((unsigned short)(u & 0xffff)) * rel_k[rr * DPH + dc * 2]
               + bf2f((unsigned short)(u >> 16))   * rel_k[rr * DPH + dc * 2 + 1];
        }
        qrel_s[r][rr] = s;
    }
    __syncthreads();

    const int srow = qstrip * 16 + sl;
    // p = exp2(qk*CEXP + qa'),  qa'_r = qrel_r*CEXP - SHIFT
    const float CEXP  = 0.125f * 1.4426950408889634f;
    const float SHIFT = 11.541560327111707f;           // 8 * log2(e)
    const float qa0 = qrel_s[srow][0] * CEXP - SHIFT;
    const float qa1 = qrel_s[srow][1] * CEXP - SHIFT;
    const float qa2 = qrel_s[srow][2] * CEXP - SHIFT;

    bf16x8 qfrag[2];
    #pragma unroll
    for (int ks = 0; ks < 2; ++ks) {
        unsigned byte = ((unsigned)srow << 7) + (unsigned)(ks << 6) + (unsigned)(tg << 4);
        byte ^= (unsigned)((srow & 7) << 4);
        qfrag[ks] = *reinterpret_cast<const bf16x8*>(smQ + byte);
    }
    // smQ's Q contents dead from here; waves 0-3 write P into it (first P
    // write is after the loop's first two barriers -> all qfrag loads done).

    const int* rrow_s = rel + ((size_t)(b * S_LEN + s0 + srow)) * S_LEN;
    unsigned char* pb = (wid < 4) ? (smQ + wid * 2048) : (smP2 + (wid - 4) * 2048);

    const int gtid  = tid & 255;      // thread id within t-group (4 waves)
    const int ldrow = gtid >> 3;      // 0..31
    const int ldkc  = gtid & 7;       // 0..7
    const unsigned wbyte0 = (((unsigned)ldrow << 7) + ((unsigned)ldkc << 4))
                            ^ ((unsigned)((ldrow & 7) << 4));
    const unsigned wbyte1 = wbyte0 + 4096;   // row+32: same swizzle bits
    unsigned char* kbase = smK  + tgroup * 8192;
    unsigned char* vbase = smVt + tgroup * 8192;

    float l_run = 0.f, es1 = 0.f, es2 = 0.f;
    f32x4 acc_pv[4] = {};

    #pragma unroll
    for (int i = 0; i < 4; ++i) {
        const int t0 = (tgroup * 4 + i) * 64;

        // issue this tile's global loads BEFORE the barrier (latency overlap)
        uint4 k0 = *reinterpret_cast<const uint4*>(ksrc + (size_t)(t0 + ldrow) * EMB + ldkc * 8);
        uint4 k1 = *reinterpret_cast<const uint4*>(ksrc + (size_t)(t0 + ldrow + 32) * EMB + ldkc * 8);
        uint4 v0 = *reinterpret_cast<const uint4*>(vsrcT + (size_t)ldrow * S_LEN + t0 + ldkc * 8);
        uint4 v1 = *reinterpret_cast<const uint4*>(vsrcT + (size_t)(ldrow + 32) * S_LEN + t0 + ldkc * 8);
        int4 rr[4];
        #pragma unroll
        for (int t4 = 0; t4 < 4; ++t4)
            rr[t4] = *reinterpret_cast<const int4*>(rrow_s + t0 + t4 * 16 + tg * 4);

        __syncthreads();   // prior compute's LDS reads done
        *reinterpret_cast<uint4*>(kbase + wbyte0) = k0;
        *reinterpret_cast<uint4*>(kbase + wbyte1) = k1;
        *reinterpret_cast<uint4*>(vbase + wbyte0) = v0;
        *reinterpret_cast<uint4*>(vbase + wbyte1) = v1;
        __syncthreads();

        // ---- QK^T: C[t][s] ----
        f32x4 sacc[4] = {};
        #pragma unroll
        for (int ks = 0; ks < 2; ++ks)
            #pragma unroll
            for (int t4 = 0; t4 < 4; ++t4) {
                int trow = t4 * 16 + sl;
                unsigned byte = ((unsigned)trow << 7) + (unsigned)(ks << 6) + (unsigned)(tg << 4);
                byte ^= (unsigned)((trow & 7) << 4);
                bf16x8 kf = *reinterpret_cast<const bf16x8*>(kbase + byte);
                sacc[t4] = __builtin_amdgcn_mfma_f32_16x16x32_bf16(kf, qfrag[ks], sacc[t4], 0, 0, 0);
            }

        // ---- no-max softmax + masked es ----
        #pragma unroll
        for (int t4 = 0; t4 < 4; ++t4) {
            int rv[4] = {rr[t4].x, rr[t4].y, rr[t4].z, rr[t4].w};
            #pragma unroll
            for (int j = 0; j < 4; ++j) {
                int r = rv[j];
                float qa = (r == 0) ? qa0 : ((r == 1) ? qa1 : qa2);
                float p = __builtin_amdgcn_exp2f(fmaf(sacc[t4][j], CEXP, qa));
                sacc[t4][j] = p;
                l_run += p;
                es1 += (r == 1) ? p : 0.f;
                es2 += (r == 2) ? p : 0.f;
            }
        }

        // P -> LDS bf16 (per-wave region; same-wave write->read)
        #pragma unroll
        for (int t4 = 0; t4 < 4; ++t4)
            #pragma unroll
            for (int pr = 0; pr < 2; ++pr) {
                unsigned u = (unsigned)f2bf(sacc[t4][2 * pr]) |
                             ((unsigned)f2bf(sacc[t4][2 * pr + 1]) << 16);
                unsigned byte = ((unsigned)sl << 7) + (unsigned)(t4 * 32 + tg * 8 + pr * 4);
                byte ^= (unsigned)((sl & 7) << 4);
                *reinterpret_cast<unsigned*>(pb + byte) = u;
            }

        // PV: acc[s][d] += P[s][t] V[t][d]
        #pragma unroll
        for (int ks = 0; ks < 2; ++ks) {
            unsigned pbyte = ((unsigned)sl << 7) + (unsigned)(ks << 6) + (unsigned)(tg << 4);
            pbyte ^= (unsigned)((sl & 7) << 4);
            bf16x8 pf = *reinterpret_cast<const bf16x8*>(pb + pbyte);
            #pragma unroll
            for (int dt = 0; dt < 4; ++dt) {
                int d = dt * 16 + sl;
                unsigned vbyte = ((unsigned)d << 7) + (unsigned)(ks << 6) + (unsigned)(tg << 4);
                vbyte ^= (unsigned)((d & 7) << 4);
                bf16x8 vf = *reinterpret_cast<const bf16x8*>(vbase + vbyte);
                acc_pv[dt] = __builtin_amdgcn_mfma_f32_16x16x32_bf16(pf, vf, acc_pv[dt], 0, 0, 0);
            }
        }
    }

    // end-only cross-lane reduce
    l_run += __shfl_xor(l_run, 16);  l_run += __shfl_xor(l_run, 32);
    es1   += __shfl_xor(es1, 16);    es1   += __shfl_xor(es1, 32);
    es2   += __shfl_xor(es2, 16);    es2   += __shfl_xor(es2, 32);

    // ---- publish partials & merge the two t-groups (weights all 1) ----
    __syncthreads();   // K/V LDS no longer needed; safe to reuse
    float* accL  = reinterpret_cast<float*>(smK);    // [64 rows][64 d]
    float* stats = reinterpret_cast<float*>(smVt);   // l[2][64], es1[2][64], es2[2][64]

    if (tg == 0) {
        stats[tgroup * 64 + srow]        = l_run;
        stats[128 + tgroup * 64 + srow]  = es1;
        stats[256 + tgroup * 64 + srow]  = es2;
    }
    if (tgroup == 1) {
        #pragma unroll
        for (int dt = 0; dt < 4; ++dt)
            #pragma unroll
            for (int r = 0; r < 4; ++r)
                accL[(qstrip * 16 + tg * 4 + r) * 64 + dt * 16 + sl] = acc_pv[dt][r];
    }
    __syncthreads();

    if (tgroup == 0) {
        unsigned short* dst = ob + ((size_t)(b * S_LEN + s0 + qstrip * 16)) * EMB + h * DPH;
        #pragma unroll
        for (int r = 0; r < 4; ++r) {
            const int row64 = qstrip * 16 + tg * 4 + r;
            float lt  = stats[row64]       + stats[64 + row64];
            float e1t = stats[128 + row64] + stats[192 + row64];
            float e2t = stats[256 + row64] + stats[320 + row64];
            float e0t = lt - e1t - e2t;
            float linv = 1.f / lt;
            #pragma unroll
            for (int dt = 0; dt < 4; ++dt) {
                int d = dt * 16 + sl;
                float o = acc_pv[dt][r] + accL[row64 * 64 + d];
                o += e0t * relv_s[0][d] + e1t * relv_s[1][d] + e2t * relv_s[2][d];
                o *= linv;
                dst[(size_t)(tg * 4 + r) * EMB + d] = f2bf(o);
            }
        }
    }
}

extern "C" void kernel_launch(void* const* d_in, const int* in_sizes, int n_in,
                              void* d_out, int out_size, void* d_ws, size_t ws_size,
                              hipStream_t stream) {
    int iq=0, ik=1, iv=2, irel=3, iWq=4, ibq=5, iWk=6, ibk=7, iWv=8, ibv=9, iWo=10, ibo=11, irk=12, irv=13;
    if (n_in >= 14 && in_sizes[0] == 512 * 512) {
        iWk=0; iWo=1; iWq=2; iWv=3; ibk=4; ibo=5; ibq=6; ibv=7;
        irel=8; ik=9; iq=10; irk=11; irv=12; iv=13;
    }

    const float* q_in = (const float*)d_in[iq];
    const float* k_in = (const float*)d_in[ik];
    const float* v_in = (const float*)d_in[iv];
    const int*   grel = (const int*)d_in[irel];
    const float* Wq = (const float*)d_in[iWq];
    const float* bq = (const float*)d_in[ibq];
    const float* Wk = (const float*)d_in[iWk];
    const float* bk = (const float*)d_in[ibk];
    const float* Wv = (const float*)d_in[iWv];
    const float* bv = (const float*)d_in[ibv];
    const float* Wo = (const float*)d_in[iWo];
    const float* bo = (const float*)d_in[ibo];
    const float* rk = (const float*)d_in[irk];
    const float* rv = (const float*)d_in[irv];

    unsigned short* qb  = (unsigned short*)d_ws;
    unsigned short* kb  = qb + (size_t)4096 * 512;
    unsigned short* vbT = kb + (size_t)4096 * 512;   // [b*NHEAD+h][d][s]
    unsigned short* ab  = vbT + (size_t)4096 * 512;
    unsigned short* wt  = ab + (size_t)4096 * 512;

    dim3 blk(256);
    transpose_w<<<dim3(8, 8, 4), blk, 0, stream>>>(Wq, Wk, Wv, Wo, wt);
    gemm_proj_mfma<<<dim3(4, 32, 3), blk, 0, stream>>>(q_in, k_in, v_in, wt, bq, bk, bv, qb, kb, vbT);
    attn_mfma<<<dim3(8, NHEAD, BATCH), dim3(512), 0, stream>>>(qb, kb, vbT, grel, rk, rv, ab);
    gemm_out_mfma<<<dim3(4, 32), blk, 0, stream>>>(ab, wt + (size_t)3 * 512 * 512, bo, (float*)d_out);
}